// Round 12
// baseline (239.396 us; speedup 1.0000x reference)
//
#include <hip/hip_runtime.h>
#include <hip/hip_bf16.h>

// Problem constants (B,N,H,W,C) = (2,512,16,32,64)
#define B_ 2
#define N_ 512
#define M_ 512
#define O1 128
#define O2 64
#define PBIG 524288.0f   // B*N*M samples for BN1/BN2
#define P3   1024.0f     // B*N samples for BN3

typedef short s8v __attribute__((ext_vector_type(8)));   // 8 bf16 (4 VGPRs)
typedef float f4v __attribute__((ext_vector_type(4)));   // MFMA accumulator

// ---- workspace layout (float-element offsets) ----
#define WS_SRCN 0        //  [B][N][64]  (dead after k2)
#define WS_DSTN 65536    //  [B][M][64]  (dead after k2 -> reused as WS_APART)
#define WS_APART 65536   //  [32][12][128] = 49152 BN1 A-coeff partials (k3sA -> k3sB)
#define WS_U    131072   //  [B][N][128] (k4 consumes; first 32K reused as WS_Z by k5)
#define WS_Z    131072   //  [B][N][32]
#define WS_V    262144   //  [B][M][128] (unscaled)
#define WS_DXY  393216   //  [B][M][2]
#define WS_COS  395264   //  [B][N][M]  -> ends 919552
#define WS_RMAX 919552   //  [B*N] INVERSE row max: 1/(max+1e-6)
#define WS_ROWS 920576   //  [3][1024] row sums (k3a)
#define WS_COLS 923648   //  [3][1024] col sums (k2r)
#define WS_A1C  926720   //  [256]: A1[128], C1[128] (k3sB)
#define WS_SC2P 935936   //  [64][16] global scalar moment partials (k3a)
#define WS_ST2  936960   //  [64][128] BN2 partials
#define WS_ST3  945152   //  [64][64]  BN3 partials
#define WS_CMAX 949248   //  [B*M] INVERSE col max
#define WS_W2F  950272   //  bf16 [8192] fragment-packed W2 (k1 -> k4, L1-resident)
#define WS_W9S  954368   //  [3][128] A1-scaled W1 rank-1 columns (k3sB)
#define WS_X2   961536   //  bf16 fragment-major [B*N][4096] uint4 (64 KB per bn)
#define WS_VF   17738752 //  [2][4][4][4096] UNSCALED V in k4 fragment order (k2 spare blocks)

__device__ __forceinline__ unsigned short f2bf(float f){
  unsigned u = __float_as_uint(f);
  unsigned r = (u + 0x7fffu + ((u >> 16) & 1u)) >> 16;   // RNE
  return (unsigned short)r;
}
__device__ __forceinline__ float bf2f(unsigned short h){
  return __uint_as_float(((unsigned)h) << 16);
}
__device__ __forceinline__ unsigned pk2(float lo, float hi){
  return (unsigned)f2bf(lo) | ((unsigned)f2bf(hi) << 16);
}
__device__ __forceinline__ unsigned pk_trunc(float lo, float hi){
  return __builtin_amdgcn_perm(__float_as_uint(hi), __float_as_uint(lo), 0x07060302u);
}
__device__ __forceinline__ f4v relu4(f4v z){
  z[0] = fmaxf(z[0], 0.f); z[1] = fmaxf(z[1], 0.f);
  z[2] = fmaxf(z[2], 0.f); z[3] = fmaxf(z[3], 0.f);
  return z;
}

// ---------------- K1: per-n (blk<1024), per-m (1024..2047), W2 pack (2048) ----------------
__global__ __launch_bounds__(128) void k1(const float* __restrict__ wxyz,
    const float* __restrict__ wpts, const float* __restrict__ lz,
    const float* __restrict__ rf3, const float* __restrict__ rf3i,
    const float* __restrict__ W1, const float* __restrict__ W2, float* __restrict__ ws){
  int t = threadIdx.x;
  if (blockIdx.x < 1024){
    int blk = blockIdx.x; int b = blk >> 9, n = blk & 511;
    int bn = b*N_ + n;
    __shared__ float wp[64]; __shared__ float sxyz[3]; __shared__ float slz; __shared__ float srn;
    if (t < 64) wp[t] = wpts[bn*64 + t];
    if (t >= 64 && t < 67) sxyz[t-64] = wxyz[bn*3 + (t-64)];
    if (t == 67) slz = lz[bn];
    __syncthreads();
    if (t < 64){
      float v = wp[t]*wp[t];
      v += __shfl_down(v,32); v += __shfl_down(v,16); v += __shfl_down(v,8);
      v += __shfl_down(v,4);  v += __shfl_down(v,2);  v += __shfl_down(v,1);
      if (t == 0) srn = 1.0f / fmaxf(sqrtf(v), 1e-12f);
    }
    __syncthreads();
    if (t < 64) ws[WS_SRCN + bn*64 + t] = wp[t]*srn;
    int o = t;
    float x = sxyz[0], y = sxyz[1], z = sxyz[2], l = slz;
    float acc = x*l*W1[0*O1+o] + y*l*W1[1*O1+o] + z*l*W1[2*O1+o]
              + wp[0]*W1[3*O1+o] + wp[1]*W1[4*O1+o]
              + x*W1[7*O1+o] + y*W1[8*O1+o];
    #pragma unroll 8
    for (int c = 0; c < 64; ++c) acc += wp[c]*W1[(10+c)*O1+o];
    ws[WS_U + bn*O1 + o] = acc;
  } else if (blockIdx.x < 2048){
    int blk = blockIdx.x - 1024; int b = blk >> 9, m = blk & 511;
    int bm = b*M_ + m;
    __shared__ float rf[64]; __shared__ float sdx, sdy, srn2;
    if (t < 64) rf[t] = rf3[(b*64 + t)*512 + m];
    if (t == 64) sdx = rf3i[(b*3 + 0)*512 + m];
    if (t == 65) sdy = rf3i[(b*3 + 1)*512 + m];
    __syncthreads();
    if (t < 64){
      float v = rf[t]*rf[t];
      v += __shfl_down(v,32); v += __shfl_down(v,16); v += __shfl_down(v,8);
      v += __shfl_down(v,4);  v += __shfl_down(v,2);  v += __shfl_down(v,1);
      if (t == 0) srn2 = 1.0f / fmaxf(sqrtf(v), 1e-12f);
    }
    __syncthreads();
    if (t < 64) ws[WS_DSTN + bm*64 + t] = rf[t]*srn2;
    if (t == 0){ ws[WS_DXY + bm*2+0] = sdx; ws[WS_DXY + bm*2+1] = sdy; }
    int o = t;
    float acc = sdx*(W1[5*O1+o] - W1[7*O1+o]) + sdy*(W1[6*O1+o] - W1[8*O1+o]);
    #pragma unroll 8
    for (int c = 0; c < 64; ++c) acc += rf[c]*W1[(74+c)*O1+o];
    ws[WS_V + bm*O1 + o] = acc;
  } else {
    // W2 fragment pack (no A1 dependence)
    unsigned short* wf = (unsigned short*)(ws + WS_W2F);
    for (int i = t; i < 8192; i += 128){
      int j = i & 7, ll = (i >> 3) & 63, ct = (i >> 9) & 3, k0q = i >> 11;
      int oo = k0q*32 + (ll >> 4)*8 + j, c = ct*16 + (ll & 15);
      wf[i] = f2bf(W2[oo*O2 + c]);
    }
  }
}

// ---------------- K2: cos matrix + row-max; spare blocks pack unscaled V fragments ----------
__global__ __launch_bounds__(256) void k2(float* __restrict__ ws){
  int blk = blockIdx.x; int t = threadIdx.x;
  if (blk >= 1024){
    // pack unscaled V into k4 fragment order (V complete after k1)
    int q = blk - 1024; int vb = q >> 4, mc = (q >> 2) & 3, w2 = q & 3;
    float* dst = ws + WS_VF + (size_t)(((vb*4 + mc)*4 + w2)*4096);
    const float* Vsrc = ws + WS_V + (size_t)vb*512*O1;
    for (int p = t; p < 4096; p += 256){
      int k0q = p >> 10, r = p & 1023, mt = r >> 9, r2 = r & 511, qr = r2 >> 3, j = r2 & 7;
      int o = k0q*32 + (qr >> 4)*8 + j;
      int m = mc*128 + w2*32 + mt*16 + (qr & 15);
      dst[p] = Vsrc[(size_t)m*O1 + o];
    }
    return;
  }
  int b = blk >> 9, n = blk & 511;
  int bn = b*N_ + n;
  __shared__ __align__(16) float sn[64];
  __shared__ float dnt[64*65];
  __shared__ float part[4*64];
  if (t < 64) sn[t] = ws[WS_SRCN + bn*64 + t];
  float lmax = -3.4e38f;
  for (int chunk = 0; chunk < 8; ++chunk){
    __syncthreads();
    const float4* src = (const float4*)(ws + WS_DSTN + (size_t)(b*M_ + chunk*64)*64);
    #pragma unroll
    for (int i = 0; i < 4; ++i){
      float4 v = src[t + i*256];
      int base = (t + i*256)*4; int mm = base >> 6, c = base & 63;
      float* dp = &dnt[mm*65 + c];
      dp[0]=v.x; dp[1]=v.y; dp[2]=v.z; dp[3]=v.w;
    }
    __syncthreads();
    {
      int mm = t & 63, cg2 = t >> 6;
      const float* dr = &dnt[mm*65 + cg2*16];
      const float* sr = &sn[cg2*16];
      float p = 0.f;
      #pragma unroll
      for (int k = 0; k < 16; ++k) p += sr[k]*dr[k];
      part[cg2*64 + mm] = p;
    }
    __syncthreads();
    if (t < 64){
      float d = part[t] + part[64+t] + part[128+t] + part[192+t];
      ws[WS_COS + bn*M_ + chunk*64 + t] = d;
      lmax = fmaxf(lmax, d);
    }
  }
  if (t < 64){
    lmax = fmaxf(lmax, __shfl_xor(lmax,32)); lmax = fmaxf(lmax, __shfl_xor(lmax,16));
    lmax = fmaxf(lmax, __shfl_xor(lmax,8));  lmax = fmaxf(lmax, __shfl_xor(lmax,4));
    lmax = fmaxf(lmax, __shfl_xor(lmax,2));  lmax = fmaxf(lmax, __shfl_xor(lmax,1));
    if (t == 0) ws[WS_RMAX + bn] = 1.0f / (lmax + 1e-6f);
  }
}

// ---------------- K2r: col maxes + col sums; spare blocks zero stat accumulators ----------
__global__ __launch_bounds__(256) void k2r(const float* __restrict__ wxyz, float* __restrict__ ws){
  int blk = blockIdx.x; int t = threadIdx.x;
  if (blk >= 64){
    // zero SC2P+ST2+ST3 (13312 @ WS_SC2P) and APART (49152 @ WS_APART)
    int zb = blk - 64;   // 0..5
    for (int i = zb*256 + t; i < 62464; i += 6*256){
      if (i < 13312) ws[WS_SC2P + i] = 0.f;
      else ws[WS_APART + (i - 13312)] = 0.f;
    }
    return;
  }
  int b = blk >> 5; int c0 = (blk & 31)*16;
  int cl = t & 15, seg = t >> 4;   // 16 segs x 32 rows
  int col = c0 + cl;
  int bm = b*M_ + col;
  float dx = ws[WS_DXY + bm*2+0], dy = ws[WS_DXY + bm*2+1];
  float mx = -3.4e38f, se = 0.f, sc = 0.f, s1c = 0.f;
  for (int i = 0; i < 32; ++i){
    int bn = b*N_ + seg*32 + i;
    float cv = ws[WS_COS + (size_t)bn*M_ + col];
    float ri = ws[WS_RMAX + bn];
    float sx = wxyz[bn*3+0], sy = wxyz[bn*3+1];
    float ex = sx-dx, ey = sy-dy;
    se += sqrtf(ex*ex + ey*ey);
    mx = fmaxf(mx, cv);
    sc += cv;
    s1c += cv*ri;
  }
  __shared__ float r0[256], r1[256], r2[256], r3[256];
  r0[t]=mx; r1[t]=se; r2[t]=s1c; r3[t]=sc;
  __syncthreads();
  for (int s = 8; s > 0; s >>= 1){
    if (seg < s){
      int o2 = t + s*16;
      r0[t] = fmaxf(r0[t], r0[o2]); r1[t] += r1[o2]; r2[t] += r2[o2]; r3[t] += r3[o2];
    }
    __syncthreads();
  }
  if (t < 16){
    int bmw = b*M_ + c0 + t;
    float ci = 1.0f/(r0[t] + 1e-10f);
    ws[WS_CMAX + bmw] = ci;
    ws[WS_COLS + bmw] = r1[t];             // CEN
    ws[WS_COLS + 1024 + bmw] = r2[t];      // CS1
    ws[WS_COLS + 2048 + bmw] = r3[t]*ci;   // CS2
  }
}

// ---------------- K3a: row sums + 9 global scalar moments from COS pass ----------------
__global__ __launch_bounds__(256) void k3a(const float* __restrict__ wxyz, float* __restrict__ ws){
  int bn = blockIdx.x; int b = bn >> 9; int t = threadIdx.x;
  float ri = ws[WS_RMAX + bn];
  float sx = wxyz[bn*3+0], sy = wxyz[bn*3+1];
  float q[9];
  #pragma unroll
  for (int j = 0; j < 9; ++j) q[j] = 0.f;
  #pragma unroll
  for (int k = 0; k < 2; ++k){
    int m = t + k*256;
    float2 d = *(const float2*)(ws + WS_DXY + (size_t)(b*M_+m)*2);
    float ex = sx-d.x, ey = sy-d.y;
    float en = sqrtf(ex*ex + ey*ey);
    float cv = ws[WS_COS + (size_t)bn*M_ + m];
    float ci = ws[WS_CMAX + b*M_ + m];
    float s2 = cv*ci;
    q[0]+=en; q[1]+=cv; q[2]+=s2; q[3]+=en*en; q[4]+=cv*cv; q[5]+=s2*s2;
    q[6]+=en*cv; q[7]+=en*s2; q[8]+=cv*cv*ci;
  }
  #pragma unroll
  for (int j = 0; j < 9; ++j){
    float v = q[j];
    v += __shfl_xor(v,1); v += __shfl_xor(v,2); v += __shfl_xor(v,4);
    v += __shfl_xor(v,8); v += __shfl_xor(v,16); v += __shfl_xor(v,32);
    q[j] = v;
  }
  __shared__ float wr[9][4];
  int w = t >> 6;
  if ((t & 63) == 0){
    #pragma unroll
    for (int j = 0; j < 9; ++j) wr[j][w] = q[j];
  }
  __syncthreads();
  if (t < 9){
    float Q = wr[t][0] + wr[t][1] + wr[t][2] + wr[t][3];
    float f = (t==1 || t==6 || t==8) ? ri : ((t==4) ? ri*ri : 1.0f);
    float s = f*Q;
    if (t < 3) ws[WS_ROWS + t*1024 + bn] = s;   // REN, RS1, RS2
    atomicAdd(&ws[WS_SC2P + (bn & 63)*16 + t], s);
  }
}

// ---------------- K3sA: BN1 A-coefficient partials (coalesced U/V reads) ----------------
// grid 256: block covers 4 rows i; thread (o = t&127, pair = t>>7) handles 2 rows.
__global__ __launch_bounds__(256) void k3sA(const float* __restrict__ b1, float* __restrict__ ws){
  int blk = blockIdx.x; int t = threadIdx.x;
  int o = t & 127, pair = t >> 7;
  float b1o = b1[o];
  float a[12];
  #pragma unroll
  for (int j = 0; j < 12; ++j) a[j] = 0.f;
  #pragma unroll
  for (int k = 0; k < 2; ++k){
    int i = blk*4 + pair*2 + k;
    float u = ws[WS_U + (size_t)i*O1 + o] + b1o;
    float v = ws[WS_V + (size_t)i*O1 + o];
    float ren = ws[WS_ROWS + i], rs1 = ws[WS_ROWS + 1024 + i], rs2 = ws[WS_ROWS + 2048 + i];
    float cen = ws[WS_COLS + i], cs1 = ws[WS_COLS + 1024 + i], cs2 = ws[WS_COLS + 2048 + i];
    a[0]+=u; a[1]+=u*u; a[2]+=u*ren; a[3]+=u*rs1; a[4]+=u*rs2;
    a[5]+=v; a[6]+=v*v; a[7]+=v*cen; a[8]+=v*cs1; a[9]+=v*cs2;
    if (i < 512){ a[10]+=u; a[11]+=v; }   // b=0 partial sums
  }
  __shared__ float apar[2][12][128];
  #pragma unroll
  for (int j = 0; j < 12; ++j) apar[pair][j][o] = a[j];
  __syncthreads();
  int rep = blk & 31;
  for (int idx = t; idx < 1536; idx += 256){
    int j = idx >> 7, oo = idx & 127;
    atomicAdd(&ws[WS_APART + rep*1536 + idx], apar[0][j][oo] + apar[1][j][oo]);
  }
}

// ---------------- K3sB: finalize closed-form BN1 -> A1/C1 + W9S (1 block) ----------------
__global__ __launch_bounds__(128) void k3sB(const float* __restrict__ W1,
    const float* __restrict__ g1, const float* __restrict__ be1, float* __restrict__ ws){
  int t = threadIdx.x; int o = t;
  __shared__ float scal[9];
  if (t < 9){
    float s = 0.f;
    #pragma unroll 8
    for (int r = 0; r < 64; ++r) s += ws[WS_SC2P + r*16 + t];
    scal[t] = s;
  }
  float A[12];
  #pragma unroll
  for (int j = 0; j < 12; ++j){
    float s = 0.f;
    #pragma unroll 8
    for (int r = 0; r < 32; ++r) s += ws[WS_APART + r*1536 + j*128 + o];
    A[j] = s;
  }
  __syncthreads();
  float w9 = W1[9*O1+o], wa = W1[138*O1+o], wb = W1[139*O1+o];
  float S1 = 512.f*(A[0] + A[5]) + w9*scal[0] + wa*scal[1] + wb*scal[2];
  float Q1 = 512.f*(A[1] + A[6])
    + 2.f*(A[10]*A[11] + (A[0]-A[10])*(A[5]-A[11]))
    + w9*w9*scal[3] + wa*wa*scal[4] + wb*wb*scal[5]
    + 2.f*(w9*wa*scal[6] + w9*wb*scal[7] + wa*wb*scal[8])
    + 2.f*(w9*A[2] + wa*A[3] + wb*A[4])
    + 2.f*(w9*A[7] + wa*A[8] + wb*A[9]);
  float mu = S1/PBIG, var = Q1/PBIG - mu*mu;
  float istd = rsqrtf(var + 1e-5f);
  float A1v = g1[o]*istd;
  ws[WS_A1C + o] = A1v;
  ws[WS_A1C + 128 + o] = be1[o] - mu*A1v;
  ws[WS_W9S + o]       = w9*A1v;
  ws[WS_W9S + 128 + o] = wa*A1v;
  ws[WS_W9S + 256 + o] = wb*A1v;
}

// ---------------- K4: P0 built from U+A1C at fill; unscaled Vf * A1 in-loop ----------
// block=256, min 4 waves/EU: NO scratch spill ((256,8) forced VGPR=32 and spilled).
__global__ __launch_bounds__(256, 4) void k4(const float* __restrict__ wxyz,
    const float* __restrict__ b1, float* __restrict__ ws){
  int blk = blockIdx.x; int bn = blk >> 2, mc = blk & 3;
  int b = bn >> 9; int t = threadIdx.x;
  __shared__ __align__(16) float p0s[128], a1s[128], w9s[128], was[128], wbs[128];
  __shared__ float ls[64], lq[64];
  if (t < 64){ ls[t] = 0.f; lq[t] = 0.f; }
  if (t < 128){
    float A1 = ws[WS_A1C + t], C1 = ws[WS_A1C + 128 + t];
    p0s[t] = (ws[WS_U + bn*O1 + t] + b1[t])*A1 + C1;
    a1s[t] = A1;
    w9s[t] = ws[WS_W9S + t];
    was[t] = ws[WS_W9S + 128 + t];
    wbs[t] = ws[WS_W9S + 256 + t];
  }
  __syncthreads();
  int ll = t & 63, w = t >> 6, l16 = ll & 15, quad = ll >> 4;
  float sx = wxyz[bn*3+0], sy = wxyz[bn*3+1];
  float ri = ws[WS_RMAX + bn];
  uint4* xf4 = (uint4*)(ws + WS_X2) + (size_t)bn*4096;
  const unsigned short* wBg = (const unsigned short*)(ws + WS_W2F);
  union U8 { s8v v; unsigned u[4]; };
  int mA = mc*128 + w*32 + l16, mB = mA + 16;
  float2 dA = *(const float2*)(ws + WS_DXY + (size_t)(b*M_+mA)*2);
  float2 dB = *(const float2*)(ws + WS_DXY + (size_t)(b*M_+mB)*2);
  float cvA = ws[WS_COS + (size_t)bn*M_ + mA], cvB = ws[WS_COS + (size_t)bn*M_ + mB];
  float ciA = ws[WS_CMAX + b*M_ + mA],         ciB = ws[WS_CMAX + b*M_ + mB];
  float exA = sx-dA.x, eyA = sy-dA.y; float en0 = sqrtf(exA*exA + eyA*eyA);
  float exB = sx-dB.x, eyB = sy-dB.y; float en1 = sqrtf(exB*exB + eyB*eyB);
  float s10 = cvA*ri, s20 = cvA*ciA;
  float s11 = cvB*ri, s21 = cvB*ciB;
  const float* vfb = ws + WS_VF + (size_t)(((b*4 + mc)*4 + w)*4096) + ll*8;
  f4v acc[2][4];
  #pragma unroll
  for (int i = 0; i < 2; ++i)
    #pragma unroll
    for (int j = 0; j < 4; ++j) acc[i][j] = (f4v){0.f,0.f,0.f,0.f};
  #pragma unroll
  for (int k0q = 0; k0q < 4; ++k0q){
    int ko = k0q*32 + quad*8;
    f4v p0a = *(const f4v*)&p0s[ko], p0b = *(const f4v*)&p0s[ko+4];
    f4v a1a = *(const f4v*)&a1s[ko], a1b = *(const f4v*)&a1s[ko+4];
    f4v w9a = *(const f4v*)&w9s[ko], w9b = *(const f4v*)&w9s[ko+4];
    f4v waa = *(const f4v*)&was[ko], wab = *(const f4v*)&was[ko+4];
    f4v wba = *(const f4v*)&wbs[ko], wbb = *(const f4v*)&wbs[ko+4];
    const float* vA = vfb + k0q*1024;
    const float* vB = vA + 512;
    f4v vA0 = *(const f4v*)(vA), vA1 = *(const f4v*)(vA + 4);
    f4v vB0 = *(const f4v*)(vB), vB1 = *(const f4v*)(vB + 4);
    f4v zaA = relu4(p0a + vA0*a1a + en0*w9a + s10*waa + s20*wba);
    f4v zbA = relu4(p0b + vA1*a1b + en0*w9b + s10*wab + s20*wbb);
    f4v zaB = relu4(p0a + vB0*a1a + en1*w9a + s11*waa + s21*wba);
    f4v zbB = relu4(p0b + vB1*a1b + en1*w9b + s11*wab + s21*wbb);
    U8 uA, uB;
    uA.u[0] = pk_trunc(zaA[0], zaA[1]); uA.u[1] = pk_trunc(zaA[2], zaA[3]);
    uA.u[2] = pk_trunc(zbA[0], zbA[1]); uA.u[3] = pk_trunc(zbA[2], zbA[3]);
    uB.u[0] = pk_trunc(zaB[0], zaB[1]); uB.u[1] = pk_trunc(zaB[2], zaB[3]);
    uB.u[2] = pk_trunc(zbB[0], zbB[1]); uB.u[3] = pk_trunc(zbB[2], zbB[3]);
    #pragma unroll
    for (int ct = 0; ct < 4; ++ct){
      s8v bw = *(const s8v*)&wBg[((k0q*4 + ct)*64 + ll)*8];
      acc[0][ct] = __builtin_amdgcn_mfma_f32_16x16x32_bf16(bw, uA.v, acc[0][ct], 0,0,0);
      acc[1][ct] = __builtin_amdgcn_mfma_f32_16x16x32_bf16(bw, uB.v, acc[1][ct], 0,0,0);
    }
  }
  #pragma unroll
  for (int mt = 0; mt < 2; ++mt){
    uint4 u0, u1;
    u0.x = pk2(acc[mt][0][0], acc[mt][0][1]); u0.y = pk2(acc[mt][0][2], acc[mt][0][3]);
    u0.z = pk2(acc[mt][1][0], acc[mt][1][1]); u0.w = pk2(acc[mt][1][2], acc[mt][1][3]);
    u1.x = pk2(acc[mt][2][0], acc[mt][2][1]); u1.y = pk2(acc[mt][2][2], acc[mt][2][3]);
    u1.z = pk2(acc[mt][3][0], acc[mt][3][1]); u1.w = pk2(acc[mt][3][2], acc[mt][3][3]);
    xf4[((((mc*4 + w)*2 + mt)*2 + 0)*64) + ll] = u0;
    xf4[((((mc*4 + w)*2 + mt)*2 + 1)*64) + ll] = u1;
  }
  #pragma unroll
  for (int ct = 0; ct < 4; ++ct){
    #pragma unroll
    for (int r = 0; r < 4; ++r){
      float a0 = acc[0][ct][r], a1 = acc[1][ct][r];
      float s = a0 + a1;
      float q = a0*a0 + a1*a1;
      s += __shfl_xor(s,1); s += __shfl_xor(s,2); s += __shfl_xor(s,4); s += __shfl_xor(s,8);
      q += __shfl_xor(q,1); q += __shfl_xor(q,2); q += __shfl_xor(q,4); q += __shfl_xor(q,8);
      if (l16 == 0){
        atomicAdd(&ls[ct*16 + quad*4 + r], s);
        atomicAdd(&lq[ct*16 + quad*4 + r], q);
      }
    }
  }
  __syncthreads();
  int rep = blk & 63;
  if (t < 64) atomicAdd(&ws[WS_ST2 + rep*128 + t], ls[t]);
  else if (t < 128) atomicAdd(&ws[WS_ST2 + rep*128 + t], lq[t-64]);
}

// ---------------- K5: BN2 + softmax pool; wave-shuffle reductions (2 barriers) ----------
__global__ __launch_bounds__(256) void k5(const float* __restrict__ g2,
    const float* __restrict__ be2, const float* __restrict__ M1w,
    const float* __restrict__ M1b, float* __restrict__ ws){
  int bn = blockIdx.x; int t = threadIdx.x;
  __shared__ float sa2[64], sc2[64];
  __shared__ float s_mx[512];
  __shared__ float s_aw[512];
  __shared__ float wred[4], wred2[4];
  __shared__ float part[64*65];
  __shared__ float s_att[64];
  if (t < 64){
    float s = 0.f, q = 0.f;
    #pragma unroll 8
    for (int r = 0; r < 64; ++r){ s += ws[WS_ST2 + r*128 + t]; q += ws[WS_ST2 + r*128 + 64 + t]; }
    float mu = s/PBIG, var = q/PBIG - mu*mu;
    float istd = rsqrtf(var + 1e-5f);
    float A2 = g2[t]*istd;
    sa2[t] = A2; sc2[t] = be2[t] - mu*A2;
  }
  __syncthreads();
  int ll = t & 63, w = t >> 6, l16 = ll & 15, quad = ll >> 4;
  const uint4* xf4 = (const uint4*)(ws + WS_X2) + (size_t)bn*4096;
  uint4 xv[4][2][2];   // [mc][mt][cp]
  #pragma unroll
  for (int mc = 0; mc < 4; ++mc)
    #pragma unroll
    for (int mt = 0; mt < 2; ++mt)
      #pragma unroll
      for (int cp = 0; cp < 2; ++cp)
        xv[mc][mt][cp] = xf4[((((mc*4 + w)*2 + mt)*2 + cp)*64) + ll];
  float a2r[4][4], c2r[4][4];
  #pragma unroll
  for (int ct = 0; ct < 4; ++ct)
    #pragma unroll
    for (int r = 0; r < 4; ++r){
      int c = ct*16 + quad*4 + r;
      a2r[ct][r] = sa2[c]; c2r[ct][r] = sc2[c];
    }
  // Pass A: per-m max over channels
  #pragma unroll
  for (int mc = 0; mc < 4; ++mc){
    #pragma unroll
    for (int mt = 0; mt < 2; ++mt){
      float mx = 0.f;   // relu >= 0
      #pragma unroll
      for (int cp = 0; cp < 2; ++cp){
        uint4 uv = xv[mc][mt][cp];
        int c0t = 2*cp, c1t = 2*cp + 1;
        float x0 = bf2f((unsigned short)(uv.x & 0xffffu));
        float x1 = bf2f((unsigned short)(uv.x >> 16));
        float x2 = bf2f((unsigned short)(uv.y & 0xffffu));
        float x3 = bf2f((unsigned short)(uv.y >> 16));
        float x4 = bf2f((unsigned short)(uv.z & 0xffffu));
        float x5 = bf2f((unsigned short)(uv.z >> 16));
        float x6 = bf2f((unsigned short)(uv.w & 0xffffu));
        float x7 = bf2f((unsigned short)(uv.w >> 16));
        mx = fmaxf(mx, a2r[c0t][0]*x0 + c2r[c0t][0]);
        mx = fmaxf(mx, a2r[c0t][1]*x1 + c2r[c0t][1]);
        mx = fmaxf(mx, a2r[c0t][2]*x2 + c2r[c0t][2]);
        mx = fmaxf(mx, a2r[c0t][3]*x3 + c2r[c0t][3]);
        mx = fmaxf(mx, a2r[c1t][0]*x4 + c2r[c1t][0]);
        mx = fmaxf(mx, a2r[c1t][1]*x5 + c2r[c1t][1]);
        mx = fmaxf(mx, a2r[c1t][2]*x6 + c2r[c1t][2]);
        mx = fmaxf(mx, a2r[c1t][3]*x7 + c2r[c1t][3]);
      }
      mx = fmaxf(mx, __shfl_xor(mx,16));
      mx = fmaxf(mx, __shfl_xor(mx,32));
      if (quad == 0) s_mx[mc*128 + w*32 + mt*16 + l16] = mx;
    }
  }
  __syncthreads();
  // global max: wave shuffle + 4-entry LDS
  {
    float v = fmaxf(s_mx[t], s_mx[t+256]);
    v = fmaxf(v, __shfl_xor(v,1));  v = fmaxf(v, __shfl_xor(v,2));
    v = fmaxf(v, __shfl_xor(v,4));  v = fmaxf(v, __shfl_xor(v,8));
    v = fmaxf(v, __shfl_xor(v,16)); v = fmaxf(v, __shfl_xor(v,32));
    if (ll == 0) wred[w] = v;
  }
  __syncthreads();
  float gmax = fmaxf(fmaxf(wred[0], wred[1]), fmaxf(wred[2], wred[3]));
  float e0 = expf(s_mx[t] - gmax), e1 = expf(s_mx[t+256] - gmax);
  s_aw[t] = e0; s_aw[t+256] = e1;
  {
    float sv = e0 + e1;
    sv += __shfl_xor(sv,1);  sv += __shfl_xor(sv,2);
    sv += __shfl_xor(sv,4);  sv += __shfl_xor(sv,8);
    sv += __shfl_xor(sv,16); sv += __shfl_xor(sv,32);
    if (ll == 0) wred2[w] = sv;
  }
  __syncthreads();
  float sinv = 1.0f / (wred2[0] + wred2[1] + wred2[2] + wred2[3]);
  // Pass C: weighted sum (y recomputed from registers)
  float acc[4][4];
  #pragma unroll
  for (int ct = 0; ct < 4; ++ct)
    #pragma unroll
    for (int r = 0; r < 4; ++r) acc[ct][r] = 0.f;
  #pragma unroll
  for (int mc = 0; mc < 4; ++mc){
    #pragma unroll
    for (int mt = 0; mt < 2; ++mt){
      float aw = s_aw[mc*128 + w*32 + mt*16 + l16];
      #pragma unroll
      for (int cp = 0; cp < 2; ++cp){
        uint4 uv = xv[mc][mt][cp];
        int c0t = 2*cp, c1t = 2*cp + 1;
        float x0 = bf2f((unsigned short)(uv.x & 0xffffu));
        float x1 = bf2f((unsigned short)(uv.x >> 16));
        float x2 = bf2f((unsigned short)(uv.y & 0xffffu));
        float x3 = bf2f((unsigned short)(uv.y >> 16));
        float x4 = bf2f((unsigned short)(uv.z & 0xffffu));
        float x5 = bf2f((unsigned short)(uv.z >> 16));
        float x6 = bf2f((unsigned short)(uv.w & 0xffffu));
        float x7 = bf2f((unsigned short)(uv.w >> 16));
        acc[c0t][0] += aw*fmaxf(a2r[c0t][0]*x0 + c2r[c0t][0], 0.f);
        acc[c0t][1] += aw*fmaxf(a2r[c0t][1]*x1 + c2r[c0t][1], 0.f);
        acc[c0t][2] += aw*fmaxf(a2r[c0t][2]*x2 + c2r[c0t][2], 0.f);
        acc[c0t][3] += aw*fmaxf(a2r[c0t][3]*x3 + c2r[c0t][3], 0.f);
        acc[c1t][0] += aw*fmaxf(a2r[c1t][0]*x4 + c2r[c1t][0], 0.f);
        acc[c1t][1] += aw*fmaxf(a2r[c1t][1]*x5 + c2r[c1t][1], 0.f);
        acc[c1t][2] += aw*fmaxf(a2r[c1t][2]*x6 + c2r[c1t][2], 0.f);
        acc[c1t][3] += aw*fmaxf(a2r[c1t][3]*x7 + c2r[c1t][3], 0.f);
      }
    }
  }
  int row = w*16 + l16;
  #pragma unroll
  for (int ct = 0; ct < 4; ++ct)
    #pragma unroll
    for (int r = 0; r < 4; ++r)
      part[row*65 + ct*16 + quad*4 + r] = acc[ct][r];
  __syncthreads();
  if (t < 64){
    float a = 0.f;
    #pragma unroll 8
    for (int r = 0; r < 64; ++r) a += part[r*65 + t];
    s_att[t] = a * sinv;
  }
  __syncthreads();
  if (t < 32){
    float z = M1b[t];
    #pragma unroll 8
    for (int c = 0; c < 64; ++c) z += s_att[c]*M1w[c*32 + t];
    ws[WS_Z + bn*32 + t] = z;
    int rep = bn & 63;
    atomicAdd(&ws[WS_ST3 + rep*64 + t], z);
    atomicAdd(&ws[WS_ST3 + rep*64 + 32 + t], z*z);
  }
}

// ---------------- K6: BN3 + head L2 -> logits ----------------
__global__ __launch_bounds__(256) void k6(const float* __restrict__ M1g,
    const float* __restrict__ M1be, const float* __restrict__ M2w,
    const float* __restrict__ M2b, const float* __restrict__ ws, float* __restrict__ out){
  int t = threadIdx.x; int s = blockIdx.x*256 + t;
  __shared__ float sa3[32], sc3[32];
  if (t < 32){
    float su = 0.f, q = 0.f;
    #pragma unroll 8
    for (int r = 0; r < 64; ++r){ su += ws[WS_ST3 + r*64 + t]; q += ws[WS_ST3 + r*64 + 32 + t]; }
    float mu = su/P3, var = q/P3 - mu*mu;
    float istd = rsqrtf(var + 1e-5f);
    float A3 = M1g[t]*istd;
    sa3[t] = A3; sc3[t] = M1be[t] - mu*A3;
  }
  __syncthreads();
  float a0 = M2b[0], a1 = M2b[1];
  #pragma unroll
  for (int j = 0; j < 32; ++j){
    float y = fmaxf(ws[WS_Z + s*32 + j]*sa3[j] + sc3[j], 0.f);
    a0 += y*M2w[j*2+0]; a1 += y*M2w[j*2+1];
  }
  out[s*2+0] = a0; out[s*2+1] = a1;
}

extern "C" void kernel_launch(void* const* d_in, const int* in_sizes, int n_in,
                              void* d_out, int out_size, void* d_ws, size_t ws_size,
                              hipStream_t stream){
  const float* wxyz = (const float*)d_in[0];
  const float* wpts = (const float*)d_in[1];
  const float* rf3  = (const float*)d_in[2];
  const float* rf3i = (const float*)d_in[3];
  const float* lz   = (const float*)d_in[4];
  const float* W1   = (const float*)d_in[5];
  const float* b1   = (const float*)d_in[6];
  const float* g1   = (const float*)d_in[7];
  const float* be1  = (const float*)d_in[8];
  const float* W2   = (const float*)d_in[9];
  const float* g2   = (const float*)d_in[11];
  const float* be2  = (const float*)d_in[12];
  const float* M1w  = (const float*)d_in[13];
  const float* M1b  = (const float*)d_in[14];
  const float* M1g  = (const float*)d_in[15];
  const float* M1be = (const float*)d_in[16];
  const float* M2w  = (const float*)d_in[17];
  const float* M2b  = (const float*)d_in[18];
  float* ws  = (float*)d_ws;
  float* out = (float*)d_out;
  k1  <<<2049,128,0,stream>>>(wxyz, wpts, lz, rf3, rf3i, W1, W2, ws);
  k2  <<<1056,256,0,stream>>>(ws);
  k2r <<<70,256,0,stream>>>(wxyz, ws);
  k3a <<<1024,256,0,stream>>>(wxyz, ws);
  k3sA<<<256,256,0,stream>>>(b1, ws);
  k3sB<<<1,128,0,stream>>>(W1, g1, be1, ws);
  k4  <<<4096,256,0,stream>>>(wxyz, b1, ws);
  k5  <<<1024,256,0,stream>>>(g2, be2, M1w, M1b, ws);
  k6  <<<4,256,0,stream>>>(M1g, M1be, M2w, M2b, ws, out);
}

// Round 13
// 214.955 us; speedup vs baseline: 1.1137x; 1.1137x over previous
//
#include <hip/hip_runtime.h>
#include <hip/hip_bf16.h>

// Problem constants (B,N,H,W,C) = (2,512,16,32,64)
#define B_ 2
#define N_ 512
#define M_ 512
#define O1 128
#define O2 64
#define PBIG 524288.0f   // B*N*M samples for BN1/BN2
#define P3   1024.0f     // B*N samples for BN3

typedef short s8v __attribute__((ext_vector_type(8)));   // 8 bf16 (4 VGPRs)
typedef float f4v __attribute__((ext_vector_type(4)));   // MFMA accumulator

// ---- workspace layout (float-element offsets) ----
#define WS_SRCN 0        //  [B][N][64]  (dead after k2 -> reused as WS_P0)
#define WS_DSTN 65536    //  [B][M][64]
#define WS_P0   0        //  [B*N][128] BN1-folded per-(b,n) part (k3s)
#define WS_U    131072   //  [B][N][128] (dead after k3s -> reused as WS_Z)
#define WS_Z    131072   //  [B][N][32]
#define WS_V    262144   //  [B][M][128] (unscaled; k3s consumes)
#define WS_DXY  393216   //  [B][M][2]
#define WS_COS  395264   //  [B][N][M]  -> ends 919552
#define WS_RMAX 919552   //  [B*N] INVERSE row max: 1/(max+1e-6)
#define WS_ROWS 920576   //  [3][1024] row sums (k3a)
#define WS_COLS 923648   //  [3][1024] col sums (k2r partials; CS2 scaled in k2f)
#define WS_SC2P 935936   //  [64][16] global scalar moment partials (k3a)
#define WS_ST2  936960   //  [64][128] BN2 partials
#define WS_ST3  945152   //  [64][64]  BN3 partials
#define WS_CMAX 949248   //  [B*M] k2r: encoded max (atomic); k2f: INVERSE col max
#define WS_W2F  950272   //  bf16 [8192] fragment-packed W2 (k1 -> k4)
#define WS_W9S  954368   //  [3][128] A1-scaled W1 rank-1 columns (k3s)
#define WS_X2   961536   //  bf16 fragment-major [B*N][4096] uint4 (64 KB per bn)
#define WS_VF   17738752 //  [2][4][4][4][2][64][8] A1-scaled V in k4 fragment order

__device__ __forceinline__ unsigned short f2bf(float f){
  unsigned u = __float_as_uint(f);
  unsigned r = (u + 0x7fffu + ((u >> 16) & 1u)) >> 16;   // RNE
  return (unsigned short)r;
}
__device__ __forceinline__ float bf2f(unsigned short h){
  return __uint_as_float(((unsigned)h) << 16);
}
__device__ __forceinline__ unsigned pk2(float lo, float hi){
  return (unsigned)f2bf(lo) | ((unsigned)f2bf(hi) << 16);
}
__device__ __forceinline__ unsigned pk_trunc(float lo, float hi){
  return __builtin_amdgcn_perm(__float_as_uint(hi), __float_as_uint(lo), 0x07060302u);
}
__device__ __forceinline__ unsigned fenc(float f){
  unsigned b = __float_as_uint(f);
  return (b & 0x80000000u) ? ~b : (b | 0x80000000u);
}
__device__ __forceinline__ float fdec(unsigned u){
  unsigned b = (u & 0x80000000u) ? (u & 0x7fffffffu) : ~u;
  return __uint_as_float(b);
}
__device__ __forceinline__ f4v relu4(f4v z){
  z[0] = fmaxf(z[0], 0.f); z[1] = fmaxf(z[1], 0.f);
  z[2] = fmaxf(z[2], 0.f); z[3] = fmaxf(z[3], 0.f);
  return z;
}

// ---------------- K1: per-n (blk<1024), per-m (1024..2047), W2 pack (2048) ----------------
__global__ __launch_bounds__(128) void k1(const float* __restrict__ wxyz,
    const float* __restrict__ wpts, const float* __restrict__ lz,
    const float* __restrict__ rf3, const float* __restrict__ rf3i,
    const float* __restrict__ W1, const float* __restrict__ W2, float* __restrict__ ws){
  int t = threadIdx.x;
  if (blockIdx.x < 1024){
    int blk = blockIdx.x; int b = blk >> 9, n = blk & 511;
    int bn = b*N_ + n;
    __shared__ float wp[64]; __shared__ float sxyz[3]; __shared__ float slz; __shared__ float srn;
    if (t < 64) wp[t] = wpts[bn*64 + t];
    if (t >= 64 && t < 67) sxyz[t-64] = wxyz[bn*3 + (t-64)];
    if (t == 67) slz = lz[bn];
    __syncthreads();
    if (t < 64){
      float v = wp[t]*wp[t];
      v += __shfl_down(v,32); v += __shfl_down(v,16); v += __shfl_down(v,8);
      v += __shfl_down(v,4);  v += __shfl_down(v,2);  v += __shfl_down(v,1);
      if (t == 0) srn = 1.0f / fmaxf(sqrtf(v), 1e-12f);
    }
    __syncthreads();
    if (t < 64) ws[WS_SRCN + bn*64 + t] = wp[t]*srn;
    int o = t;
    float x = sxyz[0], y = sxyz[1], z = sxyz[2], l = slz;
    float acc = x*l*W1[0*O1+o] + y*l*W1[1*O1+o] + z*l*W1[2*O1+o]
              + wp[0]*W1[3*O1+o] + wp[1]*W1[4*O1+o]
              + x*W1[7*O1+o] + y*W1[8*O1+o];
    #pragma unroll 8
    for (int c = 0; c < 64; ++c) acc += wp[c]*W1[(10+c)*O1+o];
    ws[WS_U + bn*O1 + o] = acc;
  } else if (blockIdx.x < 2048){
    int blk = blockIdx.x - 1024; int b = blk >> 9, m = blk & 511;
    int bm = b*M_ + m;
    __shared__ float rf[64]; __shared__ float sdx, sdy, srn2;
    if (t < 64) rf[t] = rf3[(b*64 + t)*512 + m];
    if (t == 64) sdx = rf3i[(b*3 + 0)*512 + m];
    if (t == 65) sdy = rf3i[(b*3 + 1)*512 + m];
    __syncthreads();
    if (t < 64){
      float v = rf[t]*rf[t];
      v += __shfl_down(v,32); v += __shfl_down(v,16); v += __shfl_down(v,8);
      v += __shfl_down(v,4);  v += __shfl_down(v,2);  v += __shfl_down(v,1);
      if (t == 0) srn2 = 1.0f / fmaxf(sqrtf(v), 1e-12f);
    }
    __syncthreads();
    if (t < 64) ws[WS_DSTN + bm*64 + t] = rf[t]*srn2;
    if (t == 0){ ws[WS_DXY + bm*2+0] = sdx; ws[WS_DXY + bm*2+1] = sdy; }
    int o = t;
    float acc = sdx*(W1[5*O1+o] - W1[7*O1+o]) + sdy*(W1[6*O1+o] - W1[8*O1+o]);
    #pragma unroll 8
    for (int c = 0; c < 64; ++c) acc += rf[c]*W1[(74+c)*O1+o];
    ws[WS_V + bm*O1 + o] = acc;
  } else {
    // W2 fragment pack (no A1 dependence)
    unsigned short* wf = (unsigned short*)(ws + WS_W2F);
    for (int i = t; i < 8192; i += 128){
      int j = i & 7, ll = (i >> 3) & 63, ct = (i >> 9) & 3, k0q = i >> 11;
      int oo = k0q*32 + (ll >> 4)*8 + j, c = ct*16 + (ll & 15);
      wf[i] = f2bf(W2[oo*O2 + c]);
    }
  }
}

// ---------------- K2: cos matrix + row-max (stored inverted), no atomics ----------------
__global__ __launch_bounds__(256) void k2(float* __restrict__ ws){
  int blk = blockIdx.x; int b = blk >> 9, n = blk & 511; int t = threadIdx.x;
  int bn = b*N_ + n;
  __shared__ __align__(16) float sn[64];
  __shared__ float dnt[64*65];   // +1 pad: conflict-free row reads
  __shared__ float part[4*64];
  if (t < 64) sn[t] = ws[WS_SRCN + bn*64 + t];
  float lmax = -3.4e38f;
  for (int chunk = 0; chunk < 8; ++chunk){
    __syncthreads();
    const float4* src = (const float4*)(ws + WS_DSTN + (size_t)(b*M_ + chunk*64)*64);
    #pragma unroll
    for (int i = 0; i < 4; ++i){
      float4 v = src[t + i*256];
      int base = (t + i*256)*4; int mm = base >> 6, c = base & 63;
      float* dp = &dnt[mm*65 + c];
      dp[0]=v.x; dp[1]=v.y; dp[2]=v.z; dp[3]=v.w;
    }
    __syncthreads();
    {
      int mm = t & 63, cg2 = t >> 6;
      const float* dr = &dnt[mm*65 + cg2*16];
      const float* sr = &sn[cg2*16];
      float p = 0.f;
      #pragma unroll
      for (int k = 0; k < 16; ++k) p += sr[k]*dr[k];
      part[cg2*64 + mm] = p;
    }
    __syncthreads();
    if (t < 64){
      float d = part[t] + part[64+t] + part[128+t] + part[192+t];
      ws[WS_COS + bn*M_ + chunk*64 + t] = d;
      lmax = fmaxf(lmax, d);
    }
  }
  if (t < 64){
    lmax = fmaxf(lmax, __shfl_xor(lmax,32)); lmax = fmaxf(lmax, __shfl_xor(lmax,16));
    lmax = fmaxf(lmax, __shfl_xor(lmax,8));  lmax = fmaxf(lmax, __shfl_xor(lmax,4));
    lmax = fmaxf(lmax, __shfl_xor(lmax,2));  lmax = fmaxf(lmax, __shfl_xor(lmax,1));
    if (t == 0) ws[WS_RMAX + bn] = 1.0f / (lmax + 1e-6f);
  }
}

// ---------------- K2r: col max/sum partials, 8-way row split (grid 512) ----------------
__global__ __launch_bounds__(256) void k2r(const float* __restrict__ wxyz, float* __restrict__ ws){
  int blk = blockIdx.x;            // (b*32 + cg)*8 + rs
  int rs = blk & 7; int cg = (blk >> 3) & 31; int b = blk >> 8;
  int c0 = cg*16;
  int t = threadIdx.x;
  int cl = t & 15, seg = t >> 4;   // 16 segs x 4 rows
  int col = c0 + cl;
  int bm = b*M_ + col;
  float dx = ws[WS_DXY + bm*2+0], dy = ws[WS_DXY + bm*2+1];
  float mx = -3.4e38f, se = 0.f, sc = 0.f, s1c = 0.f;
  #pragma unroll
  for (int i = 0; i < 4; ++i){
    int bn = b*N_ + rs*64 + seg*4 + i;
    float cv = ws[WS_COS + (size_t)bn*M_ + col];
    float ri = ws[WS_RMAX + bn];
    float sx = wxyz[bn*3+0], sy = wxyz[bn*3+1];
    float ex = sx-dx, ey = sy-dy;
    se += sqrtf(ex*ex + ey*ey);
    mx = fmaxf(mx, cv);
    sc += cv;
    s1c += cv*ri;
  }
  __shared__ float r0[256], r1[256], r2[256], r3[256];
  r0[t]=mx; r1[t]=se; r2[t]=s1c; r3[t]=sc;
  __syncthreads();
  for (int s = 8; s > 0; s >>= 1){
    if (seg < s){
      int o2 = t + s*16;
      r0[t] = fmaxf(r0[t], r0[o2]); r1[t] += r1[o2]; r2[t] += r2[o2]; r3[t] += r3[o2];
    }
    __syncthreads();
  }
  if (t < 16){
    int bmw = b*M_ + c0 + t;
    atomicMax((unsigned*)ws + WS_CMAX + bmw, fenc(r0[t]));
    atomicAdd(&ws[WS_COLS + bmw], r1[t]);           // CEN
    atomicAdd(&ws[WS_COLS + 1024 + bmw], r2[t]);    // CS1
    atomicAdd(&ws[WS_COLS + 2048 + bmw], r3[t]);    // raw col cv sum
  }
}

// ---------------- K2f: finalize col max (invert) + scale CS2 ----------------
__global__ __launch_bounds__(256) void k2f(float* __restrict__ ws){
  int bm = blockIdx.x*256 + threadIdx.x;
  unsigned e = ((unsigned*)ws)[WS_CMAX + bm];
  float ci = 1.0f / (fdec(e) + 1e-10f);
  ws[WS_CMAX + bm] = ci;
  ws[WS_COLS + 2048 + bm] *= ci;   // CS2 = ci * sum(cv)
}

// ---------------- K3a: row sums + 9 global scalar moments from COS pass ----------------
__global__ __launch_bounds__(256) void k3a(const float* __restrict__ wxyz, float* __restrict__ ws){
  int bn = blockIdx.x; int b = bn >> 9; int t = threadIdx.x;
  float ri = ws[WS_RMAX + bn];
  float sx = wxyz[bn*3+0], sy = wxyz[bn*3+1];
  float q[9];
  #pragma unroll
  for (int j = 0; j < 9; ++j) q[j] = 0.f;
  #pragma unroll
  for (int k = 0; k < 2; ++k){
    int m = t + k*256;
    float2 d = *(const float2*)(ws + WS_DXY + (size_t)(b*M_+m)*2);
    float ex = sx-d.x, ey = sy-d.y;
    float en = sqrtf(ex*ex + ey*ey);
    float cv = ws[WS_COS + (size_t)bn*M_ + m];
    float ci = ws[WS_CMAX + b*M_ + m];
    float s2 = cv*ci;
    q[0]+=en; q[1]+=cv; q[2]+=s2; q[3]+=en*en; q[4]+=cv*cv; q[5]+=s2*s2;
    q[6]+=en*cv; q[7]+=en*s2; q[8]+=cv*cv*ci;
  }
  #pragma unroll
  for (int j = 0; j < 9; ++j){
    float v = q[j];
    v += __shfl_xor(v,1); v += __shfl_xor(v,2); v += __shfl_xor(v,4);
    v += __shfl_xor(v,8); v += __shfl_xor(v,16); v += __shfl_xor(v,32);
    q[j] = v;
  }
  __shared__ float wr[9][4];
  int w = t >> 6;
  if ((t & 63) == 0){
    #pragma unroll
    for (int j = 0; j < 9; ++j) wr[j][w] = q[j];
  }
  __syncthreads();
  if (t < 9){
    float Q = wr[t][0] + wr[t][1] + wr[t][2] + wr[t][3];
    float f = (t==1 || t==6 || t==8) ? ri : ((t==4) ? ri*ri : 1.0f);
    float s = f*Q;
    if (t < 3) ws[WS_ROWS + t*1024 + bn] = s;   // REN, RS1, RS2
    atomicAdd(&ws[WS_SC2P + (bn & 63)*16 + t], s);
  }
}

// ---------------- K3s: closed-form BN1 per o -> A1/C1; write P0, W9S, Vf ----------------
__global__ __launch_bounds__(256) void k3s(const float* __restrict__ W1,
    const float* __restrict__ b1, const float* __restrict__ g1,
    const float* __restrict__ be1, float* __restrict__ ws){
  int o = blockIdx.x; int t = threadIdx.x;
  __shared__ float scal[9];
  __shared__ float wr[12][4];
  __shared__ float sA1, sC1;
  if (t < 9){
    float s = 0.f;
    #pragma unroll 8
    for (int r = 0; r < 64; ++r) s += ws[WS_SC2P + r*16 + t];
    scal[t] = s;
  }
  float b1o = b1[o];
  float uu[4], vv[4];
  float a[12];
  #pragma unroll
  for (int j = 0; j < 12; ++j) a[j] = 0.f;
  #pragma unroll
  for (int k = 0; k < 4; ++k){
    int i = t + k*256;
    float u = ws[WS_U + (size_t)i*O1 + o] + b1o;
    float v = ws[WS_V + (size_t)i*O1 + o];
    uu[k] = u; vv[k] = v;
    float ren = ws[WS_ROWS + i], rs1 = ws[WS_ROWS + 1024 + i], rs2 = ws[WS_ROWS + 2048 + i];
    float cen = ws[WS_COLS + i], cs1 = ws[WS_COLS + 1024 + i], cs2 = ws[WS_COLS + 2048 + i];
    a[0]+=u; a[1]+=u*u; a[2]+=u*ren; a[3]+=u*rs1; a[4]+=u*rs2;
    a[5]+=v; a[6]+=v*v; a[7]+=v*cen; a[8]+=v*cs1; a[9]+=v*cs2;
    if (k < 2){ a[10]+=u; a[11]+=v; }   // b=0 partial sums
  }
  #pragma unroll
  for (int j = 0; j < 12; ++j){
    float v = a[j];
    v += __shfl_xor(v,1); v += __shfl_xor(v,2); v += __shfl_xor(v,4);
    v += __shfl_xor(v,8); v += __shfl_xor(v,16); v += __shfl_xor(v,32);
    a[j] = v;
  }
  int w = t >> 6;
  if ((t & 63) == 0){
    #pragma unroll
    for (int j = 0; j < 12; ++j) wr[j][w] = a[j];
  }
  __syncthreads();
  if (t == 0){
    float A[12];
    #pragma unroll
    for (int j = 0; j < 12; ++j) A[j] = wr[j][0] + wr[j][1] + wr[j][2] + wr[j][3];
    float w9 = W1[9*O1+o], wa = W1[138*O1+o], wb = W1[139*O1+o];
    float S1 = 512.f*(A[0] + A[5]) + w9*scal[0] + wa*scal[1] + wb*scal[2];
    float Q1 = 512.f*(A[1] + A[6])
      + 2.f*(A[10]*A[11] + (A[0]-A[10])*(A[5]-A[11]))
      + w9*w9*scal[3] + wa*wa*scal[4] + wb*wb*scal[5]
      + 2.f*(w9*wa*scal[6] + w9*wb*scal[7] + wa*wb*scal[8])
      + 2.f*(w9*A[2] + wa*A[3] + wb*A[4])
      + 2.f*(w9*A[7] + wa*A[8] + wb*A[9]);
    float mu = S1/PBIG, var = Q1/PBIG - mu*mu;
    float istd = rsqrtf(var + 1e-5f);
    float A1v = g1[o]*istd;
    sA1 = A1v; sC1 = be1[o] - mu*A1v;
    ws[WS_W9S + o]       = w9*A1v;
    ws[WS_W9S + 128 + o] = wa*A1v;
    ws[WS_W9S + 256 + o] = wb*A1v;
  }
  __syncthreads();
  float A1 = sA1, C1 = sC1;
  int k0q = o >> 5, quad = (o >> 3) & 3, j = o & 7;
  #pragma unroll
  for (int k = 0; k < 4; ++k){
    int i = t + k*256;
    ws[WS_P0 + (size_t)i*O1 + o] = uu[k]*A1 + C1;
    int b = i >> 9, m = i & 511;
    int mc = m >> 7, w2 = (m >> 5) & 3, mt = (m >> 4) & 1, l16 = m & 15;
    ws[WS_VF + (size_t)(((b*4 + mc)*4 + w2)*4096) + k0q*1024 + mt*512 + (quad*16 + l16)*8 + j]
      = vv[k]*A1;
  }
}

// ---------------- K4: fragment-packed V loads; uint4 x2 store; no spill ----------------
// block=256, min 4 waves/EU: NO scratch spill ((256,8) forced VGPR=32 and spilled).
__global__ __launch_bounds__(256, 4) void k4(const float* __restrict__ wxyz,
    float* __restrict__ ws){
  int blk = blockIdx.x; int bn = blk >> 2, mc = blk & 3;
  int b = bn >> 9; int t = threadIdx.x;
  __shared__ __align__(16) unsigned short wBf[8192];        // 16 KB fragment-packed W2
  __shared__ __align__(16) float p0s[128], w9s[128], was[128], wbs[128];
  __shared__ float ls[64], lq[64];
  {   // stage W2 fragments: lane-consecutive 16B (conflict-free)
    const s8v* g = (const s8v*)(ws + WS_W2F);
    s8v* l = (s8v*)wBf;
    #pragma unroll
    for (int c2 = 0; c2 < 4; ++c2) l[c2*256 + t] = g[c2*256 + t];
  }
  if (t < 64){ ls[t] = 0.f; lq[t] = 0.f; }
  if (t < 128){
    p0s[t] = ws[WS_P0 + bn*O1 + t];
    w9s[t] = ws[WS_W9S + t];
    was[t] = ws[WS_W9S + 128 + t];
    wbs[t] = ws[WS_W9S + 256 + t];
  }
  __syncthreads();
  int ll = t & 63, w = t >> 6, l16 = ll & 15, quad = ll >> 4;
  float sx = wxyz[bn*3+0], sy = wxyz[bn*3+1];
  float ri = ws[WS_RMAX + bn];
  uint4* xf4 = (uint4*)(ws + WS_X2) + (size_t)bn*4096;
  union U8 { s8v v; unsigned u[4]; };
  int mA = mc*128 + w*32 + l16, mB = mA + 16;
  float2 dA = *(const float2*)(ws + WS_DXY + (size_t)(b*M_+mA)*2);
  float2 dB = *(const float2*)(ws + WS_DXY + (size_t)(b*M_+mB)*2);
  float cvA = ws[WS_COS + (size_t)bn*M_ + mA], cvB = ws[WS_COS + (size_t)bn*M_ + mB];
  float ciA = ws[WS_CMAX + b*M_ + mA],         ciB = ws[WS_CMAX + b*M_ + mB];
  float exA = sx-dA.x, eyA = sy-dA.y; float en0 = sqrtf(exA*exA + eyA*eyA);
  float exB = sx-dB.x, eyB = sy-dB.y; float en1 = sqrtf(exB*exB + eyB*eyB);
  float s10 = cvA*ri, s20 = cvA*ciA;
  float s11 = cvB*ri, s21 = cvB*ciB;
  const float* vfb = ws + WS_VF + (size_t)(((b*4 + mc)*4 + w)*4096) + ll*8;
  f4v acc[2][4];
  #pragma unroll
  for (int i = 0; i < 2; ++i)
    #pragma unroll
    for (int j = 0; j < 4; ++j) acc[i][j] = (f4v){0.f,0.f,0.f,0.f};
  #pragma unroll
  for (int k0q = 0; k0q < 4; ++k0q){
    int ko = k0q*32 + quad*8;
    f4v p0a = *(const f4v*)&p0s[ko], p0b = *(const f4v*)&p0s[ko+4];
    f4v w9a = *(const f4v*)&w9s[ko], w9b = *(const f4v*)&w9s[ko+4];
    f4v waa = *(const f4v*)&was[ko], wab = *(const f4v*)&was[ko+4];
    f4v wba = *(const f4v*)&wbs[ko], wbb = *(const f4v*)&wbs[ko+4];
    const float* vA = vfb + k0q*1024;
    const float* vB = vA + 512;
    f4v vA0 = *(const f4v*)(vA), vA1 = *(const f4v*)(vA + 4);
    f4v vB0 = *(const f4v*)(vB), vB1 = *(const f4v*)(vB + 4);
    f4v zaA = relu4(p0a + vA0 + en0*w9a + s10*waa + s20*wba);
    f4v zbA = relu4(p0b + vA1 + en0*w9b + s10*wab + s20*wbb);
    f4v zaB = relu4(p0a + vB0 + en1*w9a + s11*waa + s21*wba);
    f4v zbB = relu4(p0b + vB1 + en1*w9b + s11*wab + s21*wbb);
    U8 uA, uB;
    uA.u[0] = pk_trunc(zaA[0], zaA[1]); uA.u[1] = pk_trunc(zaA[2], zaA[3]);
    uA.u[2] = pk_trunc(zbA[0], zbA[1]); uA.u[3] = pk_trunc(zbA[2], zbA[3]);
    uB.u[0] = pk_trunc(zaB[0], zaB[1]); uB.u[1] = pk_trunc(zaB[2], zaB[3]);
    uB.u[2] = pk_trunc(zbB[0], zbB[1]); uB.u[3] = pk_trunc(zbB[2], zbB[3]);
    #pragma unroll
    for (int ct = 0; ct < 4; ++ct){
      s8v bw = *(const s8v*)&wBf[((k0q*4 + ct)*64 + ll)*8];
      acc[0][ct] = __builtin_amdgcn_mfma_f32_16x16x32_bf16(bw, uA.v, acc[0][ct], 0,0,0);
      acc[1][ct] = __builtin_amdgcn_mfma_f32_16x16x32_bf16(bw, uB.v, acc[1][ct], 0,0,0);
    }
  }
  // fragment-major store, 16 B/lane: wave writes 1024 B contiguous per inst
  #pragma unroll
  for (int mt = 0; mt < 2; ++mt){
    uint4 u0, u1;
    u0.x = pk2(acc[mt][0][0], acc[mt][0][1]); u0.y = pk2(acc[mt][0][2], acc[mt][0][3]);
    u0.z = pk2(acc[mt][1][0], acc[mt][1][1]); u0.w = pk2(acc[mt][1][2], acc[mt][1][3]);
    u1.x = pk2(acc[mt][2][0], acc[mt][2][1]); u1.y = pk2(acc[mt][2][2], acc[mt][2][3]);
    u1.z = pk2(acc[mt][3][0], acc[mt][3][1]); u1.w = pk2(acc[mt][3][2], acc[mt][3][3]);
    xf4[((((mc*4 + w)*2 + mt)*2 + 0)*64) + ll] = u0;
    xf4[((((mc*4 + w)*2 + mt)*2 + 1)*64) + ll] = u1;
  }
  // BN2 stat reduce: over the 16 lanes of each quad-group, then LDS
  #pragma unroll
  for (int ct = 0; ct < 4; ++ct){
    #pragma unroll
    for (int r = 0; r < 4; ++r){
      float a0 = acc[0][ct][r], a1 = acc[1][ct][r];
      float s = a0 + a1;
      float q = a0*a0 + a1*a1;
      s += __shfl_xor(s,1); s += __shfl_xor(s,2); s += __shfl_xor(s,4); s += __shfl_xor(s,8);
      q += __shfl_xor(q,1); q += __shfl_xor(q,2); q += __shfl_xor(q,4); q += __shfl_xor(q,8);
      if (l16 == 0){
        atomicAdd(&ls[ct*16 + quad*4 + r], s);
        atomicAdd(&lq[ct*16 + quad*4 + r], q);
      }
    }
  }
  __syncthreads();
  int rep = blk & 63;
  if (t < 64) atomicAdd(&ws[WS_ST2 + rep*128 + t], ls[t]);
  else if (t < 128) atomicAdd(&ws[WS_ST2 + rep*128 + t], lq[t-64]);
}

// ---------------- K5: BN2 + softmax pool from uint4 fragment-major x2 ----------------
__global__ __launch_bounds__(256) void k5(const float* __restrict__ g2,
    const float* __restrict__ be2, const float* __restrict__ M1w,
    const float* __restrict__ M1b, float* __restrict__ ws){
  int bn = blockIdx.x; int t = threadIdx.x;
  __shared__ float sa2[64], sc2[64];
  __shared__ float s_mx[512];
  __shared__ float s_aw[512];
  __shared__ float red[256];
  __shared__ float part[64*65];
  __shared__ float s_att[64];
  __shared__ float sgmax, sinvS;
  if (t < 64){
    float s = 0.f, q = 0.f;
    #pragma unroll 8
    for (int r = 0; r < 64; ++r){ s += ws[WS_ST2 + r*128 + t]; q += ws[WS_ST2 + r*128 + 64 + t]; }
    float mu = s/PBIG, var = q/PBIG - mu*mu;
    float istd = rsqrtf(var + 1e-5f);
    float A2 = g2[t]*istd;
    sa2[t] = A2; sc2[t] = be2[t] - mu*A2;
  }
  __syncthreads();
  int ll = t & 63, w = t >> 6, l16 = ll & 15, quad = ll >> 4;
  const uint4* xf4 = (const uint4*)(ws + WS_X2) + (size_t)bn*4096;
  uint4 xv[4][2][2];   // [mc][mt][cp]
  #pragma unroll
  for (int mc = 0; mc < 4; ++mc)
    #pragma unroll
    for (int mt = 0; mt < 2; ++mt)
      #pragma unroll
      for (int cp = 0; cp < 2; ++cp)
        xv[mc][mt][cp] = xf4[((((mc*4 + w)*2 + mt)*2 + cp)*64) + ll];
  float a2r[4][4], c2r[4][4];
  #pragma unroll
  for (int ct = 0; ct < 4; ++ct)
    #pragma unroll
    for (int r = 0; r < 4; ++r){
      int c = ct*16 + quad*4 + r;
      a2r[ct][r] = sa2[c]; c2r[ct][r] = sc2[c];
    }
  // Pass A: per-m max over channels; 2 shuffles (across quads)
  #pragma unroll
  for (int mc = 0; mc < 4; ++mc){
    #pragma unroll
    for (int mt = 0; mt < 2; ++mt){
      float mx = 0.f;   // relu >= 0
      #pragma unroll
      for (int cp = 0; cp < 2; ++cp){
        uint4 uv = xv[mc][mt][cp];
        int c0t = 2*cp, c1t = 2*cp + 1;
        float x0 = bf2f((unsigned short)(uv.x & 0xffffu));
        float x1 = bf2f((unsigned short)(uv.x >> 16));
        float x2 = bf2f((unsigned short)(uv.y & 0xffffu));
        float x3 = bf2f((unsigned short)(uv.y >> 16));
        float x4 = bf2f((unsigned short)(uv.z & 0xffffu));
        float x5 = bf2f((unsigned short)(uv.z >> 16));
        float x6 = bf2f((unsigned short)(uv.w & 0xffffu));
        float x7 = bf2f((unsigned short)(uv.w >> 16));
        mx = fmaxf(mx, a2r[c0t][0]*x0 + c2r[c0t][0]);
        mx = fmaxf(mx, a2r[c0t][1]*x1 + c2r[c0t][1]);
        mx = fmaxf(mx, a2r[c0t][2]*x2 + c2r[c0t][2]);
        mx = fmaxf(mx, a2r[c0t][3]*x3 + c2r[c0t][3]);
        mx = fmaxf(mx, a2r[c1t][0]*x4 + c2r[c1t][0]);
        mx = fmaxf(mx, a2r[c1t][1]*x5 + c2r[c1t][1]);
        mx = fmaxf(mx, a2r[c1t][2]*x6 + c2r[c1t][2]);
        mx = fmaxf(mx, a2r[c1t][3]*x7 + c2r[c1t][3]);
      }
      mx = fmaxf(mx, __shfl_xor(mx,16));
      mx = fmaxf(mx, __shfl_xor(mx,32));
      if (quad == 0) s_mx[mc*128 + w*32 + mt*16 + l16] = mx;
    }
  }
  __syncthreads();
  red[t] = fmaxf(s_mx[t], s_mx[t+256]);
  __syncthreads();
  for (int s = 128; s > 0; s >>= 1){ if (t < s) red[t] = fmaxf(red[t], red[t+s]); __syncthreads(); }
  if (t == 0) sgmax = red[0];
  __syncthreads();
  float e0 = expf(s_mx[t] - sgmax), e1 = expf(s_mx[t+256] - sgmax);
  s_aw[t] = e0; s_aw[t+256] = e1;
  red[t] = e0 + e1;
  __syncthreads();
  for (int s = 128; s > 0; s >>= 1){ if (t < s) red[t] += red[t+s]; __syncthreads(); }
  if (t == 0) sinvS = 1.0f / red[0];
  __syncthreads();
  // Pass C: weighted sum (y recomputed from registers)
  float acc[4][4];
  #pragma unroll
  for (int ct = 0; ct < 4; ++ct)
    #pragma unroll
    for (int r = 0; r < 4; ++r) acc[ct][r] = 0.f;
  #pragma unroll
  for (int mc = 0; mc < 4; ++mc){
    #pragma unroll
    for (int mt = 0; mt < 2; ++mt){
      float aw = s_aw[mc*128 + w*32 + mt*16 + l16];
      #pragma unroll
      for (int cp = 0; cp < 2; ++cp){
        uint4 uv = xv[mc][mt][cp];
        int c0t = 2*cp, c1t = 2*cp + 1;
        float x0 = bf2f((unsigned short)(uv.x & 0xffffu));
        float x1 = bf2f((unsigned short)(uv.x >> 16));
        float x2 = bf2f((unsigned short)(uv.y & 0xffffu));
        float x3 = bf2f((unsigned short)(uv.y >> 16));
        float x4 = bf2f((unsigned short)(uv.z & 0xffffu));
        float x5 = bf2f((unsigned short)(uv.z >> 16));
        float x6 = bf2f((unsigned short)(uv.w & 0xffffu));
        float x7 = bf2f((unsigned short)(uv.w >> 16));
        acc[c0t][0] += aw*fmaxf(a2r[c0t][0]*x0 + c2r[c0t][0], 0.f);
        acc[c0t][1] += aw*fmaxf(a2r[c0t][1]*x1 + c2r[c0t][1], 0.f);
        acc[c0t][2] += aw*fmaxf(a2r[c0t][2]*x2 + c2r[c0t][2], 0.f);
        acc[c0t][3] += aw*fmaxf(a2r[c0t][3]*x3 + c2r[c0t][3], 0.f);
        acc[c1t][0] += aw*fmaxf(a2r[c1t][0]*x4 + c2r[c1t][0], 0.f);
        acc[c1t][1] += aw*fmaxf(a2r[c1t][1]*x5 + c2r[c1t][1], 0.f);
        acc[c1t][2] += aw*fmaxf(a2r[c1t][2]*x6 + c2r[c1t][2], 0.f);
        acc[c1t][3] += aw*fmaxf(a2r[c1t][3]*x7 + c2r[c1t][3], 0.f);
      }
    }
  }
  int row = w*16 + l16;
  #pragma unroll
  for (int ct = 0; ct < 4; ++ct)
    #pragma unroll
    for (int r = 0; r < 4; ++r)
      part[row*65 + ct*16 + quad*4 + r] = acc[ct][r];
  __syncthreads();
  if (t < 64){
    float a = 0.f;
    #pragma unroll 8
    for (int r = 0; r < 64; ++r) a += part[r*65 + t];
    s_att[t] = a * sinvS;
  }
  __syncthreads();
  if (t < 32){
    float z = M1b[t];
    #pragma unroll 8
    for (int c = 0; c < 64; ++c) z += s_att[c]*M1w[c*32 + t];
    ws[WS_Z + bn*32 + t] = z;
    int rep = bn & 63;
    atomicAdd(&ws[WS_ST3 + rep*64 + t], z);
    atomicAdd(&ws[WS_ST3 + rep*64 + 32 + t], z*z);
  }
}

// ---------------- K6: BN3 + head L2 -> logits ----------------
__global__ __launch_bounds__(256) void k6(const float* __restrict__ M1g,
    const float* __restrict__ M1be, const float* __restrict__ M2w,
    const float* __restrict__ M2b, const float* __restrict__ ws, float* __restrict__ out){
  int t = threadIdx.x; int s = blockIdx.x*256 + t;
  __shared__ float sa3[32], sc3[32];
  if (t < 32){
    float su = 0.f, q = 0.f;
    #pragma unroll 8
    for (int r = 0; r < 64; ++r){ su += ws[WS_ST3 + r*64 + t]; q += ws[WS_ST3 + r*64 + 32 + t]; }
    float mu = su/P3, var = q/P3 - mu*mu;
    float istd = rsqrtf(var + 1e-5f);
    float A3 = M1g[t]*istd;
    sa3[t] = A3; sc3[t] = M1be[t] - mu*A3;
  }
  __syncthreads();
  float a0 = M2b[0], a1 = M2b[1];
  #pragma unroll
  for (int j = 0; j < 32; ++j){
    float y = fmaxf(ws[WS_Z + s*32 + j]*sa3[j] + sc3[j], 0.f);
    a0 += y*M2w[j*2+0]; a1 += y*M2w[j*2+1];
  }
  out[s*2+0] = a0; out[s*2+1] = a1;
}

extern "C" void kernel_launch(void* const* d_in, const int* in_sizes, int n_in,
                              void* d_out, int out_size, void* d_ws, size_t ws_size,
                              hipStream_t stream){
  const float* wxyz = (const float*)d_in[0];
  const float* wpts = (const float*)d_in[1];
  const float* rf3  = (const float*)d_in[2];
  const float* rf3i = (const float*)d_in[3];
  const float* lz   = (const float*)d_in[4];
  const float* W1   = (const float*)d_in[5];
  const float* b1   = (const float*)d_in[6];
  const float* g1   = (const float*)d_in[7];
  const float* be1  = (const float*)d_in[8];
  const float* W2   = (const float*)d_in[9];
  const float* g2   = (const float*)d_in[11];
  const float* be2  = (const float*)d_in[12];
  const float* M1w  = (const float*)d_in[13];
  const float* M1b  = (const float*)d_in[14];
  const float* M1g  = (const float*)d_in[15];
  const float* M1be = (const float*)d_in[16];
  const float* M2w  = (const float*)d_in[17];
  const float* M2b  = (const float*)d_in[18];
  float* ws  = (float*)d_ws;
  float* out = (float*)d_out;
  // zero SC2P+ST2+ST3+CMAX (contiguous 935936..950272 = 14336 floats) and COLS (3072)
  hipMemsetAsync(ws + WS_SC2P, 0, 14336*sizeof(float), stream);
  hipMemsetAsync(ws + WS_COLS, 0, 3072*sizeof(float), stream);
  k1 <<<2049,128,0,stream>>>(wxyz, wpts, lz, rf3, rf3i, W1, W2, ws);
  k2 <<<1024,256,0,stream>>>(ws);
  k2r<<<512,256,0,stream>>>(wxyz, ws);
  k2f<<<4,256,0,stream>>>(ws);
  k3a<<<1024,256,0,stream>>>(wxyz, ws);
  k3s<<<128,256,0,stream>>>(W1, b1, g1, be1, ws);
  k4 <<<4096,256,0,stream>>>(wxyz, ws);
  k5 <<<1024,256,0,stream>>>(g2, be2, M1w, M1b, ws);
  k6 <<<4,256,0,stream>>>(M1g, M1be, M2w, M2b, ws, out);
}

// Round 14
// 210.480 us; speedup vs baseline: 1.1374x; 1.0213x over previous
//
#include <hip/hip_runtime.h>
#include <hip/hip_bf16.h>

// Problem constants (B,N,H,W,C) = (2,512,16,32,64)
#define B_ 2
#define N_ 512
#define M_ 512
#define O1 128
#define O2 64
#define PBIG 524288.0f   // B*N*M samples for BN1/BN2
#define P3   1024.0f     // B*N samples for BN3

typedef short s8v __attribute__((ext_vector_type(8)));   // 8 bf16 (4 VGPRs)
typedef float f4v __attribute__((ext_vector_type(4)));   // MFMA accumulator

// ---- workspace layout (float-element offsets) ----
#define WS_SRCN 0        //  [B][N][64]  (dead after k2 -> reused as WS_P0)
#define WS_DSTN 65536    //  [B][M][64]
#define WS_P0   0        //  [B*N][128] BN1-folded per-(b,n) part (k3s)
#define WS_U    131072   //  [B][N][128] (dead after k3s -> reused as WS_Z)
#define WS_Z    131072   //  [B][N][32]
#define WS_V    262144   //  [B][M][128] (unscaled; k3s consumes)
#define WS_DXY  393216   //  [B][M][2]
#define WS_COS  395264   //  [B][N][M]  -> ends 919552
#define WS_RMAX 919552   //  [B*N] INVERSE row max: 1/(max+1e-6)
#define WS_ROWS 920576   //  [3][1024] row sums (k3a)
#define WS_COLS 923648   //  [3][1024] col sums (k2r partials; CS2 raw, scaled in k3s)
#define WS_SC2P 935936   //  [64][16] global scalar moment partials (k3a)
#define WS_ST2  936960   //  [64][128] BN2 partials
#define WS_ST3  945152   //  [64][64]  BN3 partials
#define WS_CMAX 949248   //  [B*M] ENCODED col max (k2r atomicMax); consumers decode inline
#define WS_W2F  950272   //  bf16 [8192] fragment-packed W2 (k1 -> k4)
#define WS_W9S  954368   //  [3][128] A1-scaled W1 rank-1 columns (k3s)
#define WS_X2   961536   //  bf16 fragment-major [B*N][4096] uint4 (64 KB per bn)
#define WS_VF   17738752 //  [2][4][4][4][2][64][8] A1-scaled V in k4 fragment order

__device__ __forceinline__ unsigned short f2bf(float f){
  unsigned u = __float_as_uint(f);
  unsigned r = (u + 0x7fffu + ((u >> 16) & 1u)) >> 16;   // RNE
  return (unsigned short)r;
}
__device__ __forceinline__ float bf2f(unsigned short h){
  return __uint_as_float(((unsigned)h) << 16);
}
__device__ __forceinline__ unsigned pk2(float lo, float hi){
  return (unsigned)f2bf(lo) | ((unsigned)f2bf(hi) << 16);
}
__device__ __forceinline__ unsigned pk_trunc(float lo, float hi){
  return __builtin_amdgcn_perm(__float_as_uint(hi), __float_as_uint(lo), 0x07060302u);
}
__device__ __forceinline__ unsigned fenc(float f){
  unsigned b = __float_as_uint(f);
  return (b & 0x80000000u) ? ~b : (b | 0x80000000u);
}
__device__ __forceinline__ float fdec(unsigned u){
  unsigned b = (u & 0x80000000u) ? (u & 0x7fffffffu) : ~u;
  return __uint_as_float(b);
}
__device__ __forceinline__ float cinv(unsigned e){   // decode + invert col max
  return 1.0f / (fdec(e) + 1e-10f);
}
__device__ __forceinline__ f4v relu4(f4v z){
  z[0] = fmaxf(z[0], 0.f); z[1] = fmaxf(z[1], 0.f);
  z[2] = fmaxf(z[2], 0.f); z[3] = fmaxf(z[3], 0.f);
  return z;
}

// ---------------- K1: per-n (blk<1024), per-m (1024..2047), W2 pack (2048) ----------------
__global__ __launch_bounds__(128) void k1(const float* __restrict__ wxyz,
    const float* __restrict__ wpts, const float* __restrict__ lz,
    const float* __restrict__ rf3, const float* __restrict__ rf3i,
    const float* __restrict__ W1, const float* __restrict__ W2, float* __restrict__ ws){
  int t = threadIdx.x;
  if (blockIdx.x < 1024){
    int blk = blockIdx.x; int b = blk >> 9, n = blk & 511;
    int bn = b*N_ + n;
    __shared__ float wp[64]; __shared__ float sxyz[3]; __shared__ float slz; __shared__ float srn;
    if (t < 64) wp[t] = wpts[bn*64 + t];
    if (t >= 64 && t < 67) sxyz[t-64] = wxyz[bn*3 + (t-64)];
    if (t == 67) slz = lz[bn];
    __syncthreads();
    if (t < 64){
      float v = wp[t]*wp[t];
      v += __shfl_down(v,32); v += __shfl_down(v,16); v += __shfl_down(v,8);
      v += __shfl_down(v,4);  v += __shfl_down(v,2);  v += __shfl_down(v,1);
      if (t == 0) srn = 1.0f / fmaxf(sqrtf(v), 1e-12f);
    }
    __syncthreads();
    if (t < 64) ws[WS_SRCN + bn*64 + t] = wp[t]*srn;
    int o = t;
    float x = sxyz[0], y = sxyz[1], z = sxyz[2], l = slz;
    float acc = x*l*W1[0*O1+o] + y*l*W1[1*O1+o] + z*l*W1[2*O1+o]
              + wp[0]*W1[3*O1+o] + wp[1]*W1[4*O1+o]
              + x*W1[7*O1+o] + y*W1[8*O1+o];
    #pragma unroll 8
    for (int c = 0; c < 64; ++c) acc += wp[c]*W1[(10+c)*O1+o];
    ws[WS_U + bn*O1 + o] = acc;
  } else if (blockIdx.x < 2048){
    int blk = blockIdx.x - 1024; int b = blk >> 9, m = blk & 511;
    int bm = b*M_ + m;
    __shared__ float rf[64]; __shared__ float sdx, sdy, srn2;
    if (t < 64) rf[t] = rf3[(b*64 + t)*512 + m];
    if (t == 64) sdx = rf3i[(b*3 + 0)*512 + m];
    if (t == 65) sdy = rf3i[(b*3 + 1)*512 + m];
    __syncthreads();
    if (t < 64){
      float v = rf[t]*rf[t];
      v += __shfl_down(v,32); v += __shfl_down(v,16); v += __shfl_down(v,8);
      v += __shfl_down(v,4);  v += __shfl_down(v,2);  v += __shfl_down(v,1);
      if (t == 0) srn2 = 1.0f / fmaxf(sqrtf(v), 1e-12f);
    }
    __syncthreads();
    if (t < 64) ws[WS_DSTN + bm*64 + t] = rf[t]*srn2;
    if (t == 0){ ws[WS_DXY + bm*2+0] = sdx; ws[WS_DXY + bm*2+1] = sdy; }
    int o = t;
    float acc = sdx*(W1[5*O1+o] - W1[7*O1+o]) + sdy*(W1[6*O1+o] - W1[8*O1+o]);
    #pragma unroll 8
    for (int c = 0; c < 64; ++c) acc += rf[c]*W1[(74+c)*O1+o];
    ws[WS_V + bm*O1 + o] = acc;
  } else {
    // W2 fragment pack (no A1 dependence)
    unsigned short* wf = (unsigned short*)(ws + WS_W2F);
    for (int i = t; i < 8192; i += 128){
      int j = i & 7, ll = (i >> 3) & 63, ct = (i >> 9) & 3, k0q = i >> 11;
      int oo = k0q*32 + (ll >> 4)*8 + j, c = ct*16 + (ll & 15);
      wf[i] = f2bf(W2[oo*O2 + c]);
    }
  }
}

// ---------------- K2: cos matrix + row-max; spare blocks zero COLS+CMAX (pre-k2r) --------
__global__ __launch_bounds__(256) void k2(float* __restrict__ ws){
  int blk = blockIdx.x; int t = threadIdx.x;
  if (blk >= 1024){
    // zero COLS (3072) + CMAX (1024) before k2r's atomics
    int i = (blk - 1024)*256 + t;   // 4 blocks x 256 = 1024 strides of 4
    #pragma unroll
    for (int j = 0; j < 4; ++j){
      int idx = i + j*1024;
      if (idx < 3072) ws[WS_COLS + idx] = 0.f;
    }
    ((unsigned*)ws)[WS_CMAX + i] = 0u;
    return;
  }
  int b = blk >> 9, n = blk & 511;
  int bn = b*N_ + n;
  __shared__ __align__(16) float sn[64];
  __shared__ float dnt[64*65];   // +1 pad: conflict-free row reads
  __shared__ float part[4*64];
  if (t < 64) sn[t] = ws[WS_SRCN + bn*64 + t];
  float lmax = -3.4e38f;
  for (int chunk = 0; chunk < 8; ++chunk){
    __syncthreads();
    const float4* src = (const float4*)(ws + WS_DSTN + (size_t)(b*M_ + chunk*64)*64);
    #pragma unroll
    for (int i = 0; i < 4; ++i){
      float4 v = src[t + i*256];
      int base = (t + i*256)*4; int mm = base >> 6, c = base & 63;
      float* dp = &dnt[mm*65 + c];
      dp[0]=v.x; dp[1]=v.y; dp[2]=v.z; dp[3]=v.w;
    }
    __syncthreads();
    {
      int mm = t & 63, cg2 = t >> 6;
      const float* dr = &dnt[mm*65 + cg2*16];
      const float* sr = &sn[cg2*16];
      float p = 0.f;
      #pragma unroll
      for (int k = 0; k < 16; ++k) p += sr[k]*dr[k];
      part[cg2*64 + mm] = p;
    }
    __syncthreads();
    if (t < 64){
      float d = part[t] + part[64+t] + part[128+t] + part[192+t];
      ws[WS_COS + bn*M_ + chunk*64 + t] = d;
      lmax = fmaxf(lmax, d);
    }
  }
  if (t < 64){
    lmax = fmaxf(lmax, __shfl_xor(lmax,32)); lmax = fmaxf(lmax, __shfl_xor(lmax,16));
    lmax = fmaxf(lmax, __shfl_xor(lmax,8));  lmax = fmaxf(lmax, __shfl_xor(lmax,4));
    lmax = fmaxf(lmax, __shfl_xor(lmax,2));  lmax = fmaxf(lmax, __shfl_xor(lmax,1));
    if (t == 0) ws[WS_RMAX + bn] = 1.0f / (lmax + 1e-6f);
  }
}

// ---------------- K2r: col max/sum partials, 8-way row split (grid 512) ----------------
__global__ __launch_bounds__(256) void k2r(const float* __restrict__ wxyz, float* __restrict__ ws){
  int blk = blockIdx.x;            // (b*32 + cg)*8 + rs
  int rs = blk & 7; int cg = (blk >> 3) & 31; int b = blk >> 8;
  int c0 = cg*16;
  int t = threadIdx.x;
  int cl = t & 15, seg = t >> 4;   // 16 segs x 4 rows
  int col = c0 + cl;
  int bm = b*M_ + col;
  float dx = ws[WS_DXY + bm*2+0], dy = ws[WS_DXY + bm*2+1];
  float mx = -3.4e38f, se = 0.f, sc = 0.f, s1c = 0.f;
  #pragma unroll
  for (int i = 0; i < 4; ++i){
    int bn = b*N_ + rs*64 + seg*4 + i;
    float cv = ws[WS_COS + (size_t)bn*M_ + col];
    float ri = ws[WS_RMAX + bn];
    float sx = wxyz[bn*3+0], sy = wxyz[bn*3+1];
    float ex = sx-dx, ey = sy-dy;
    se += sqrtf(ex*ex + ey*ey);
    mx = fmaxf(mx, cv);
    sc += cv;
    s1c += cv*ri;
  }
  __shared__ float r0[256], r1[256], r2[256], r3[256];
  r0[t]=mx; r1[t]=se; r2[t]=s1c; r3[t]=sc;
  __syncthreads();
  for (int s = 8; s > 0; s >>= 1){
    if (seg < s){
      int o2 = t + s*16;
      r0[t] = fmaxf(r0[t], r0[o2]); r1[t] += r1[o2]; r2[t] += r2[o2]; r3[t] += r3[o2];
    }
    __syncthreads();
  }
  if (t < 16){
    int bmw = b*M_ + c0 + t;
    atomicMax((unsigned*)ws + WS_CMAX + bmw, fenc(r0[t]));
    atomicAdd(&ws[WS_COLS + bmw], r1[t]);           // CEN
    atomicAdd(&ws[WS_COLS + 1024 + bmw], r2[t]);    // CS1
    atomicAdd(&ws[WS_COLS + 2048 + bmw], r3[t]);    // raw col cv sum
  }
}

// ---------------- K3a: row sums + 9 global scalar moments (CMAX decoded inline) ----------
__global__ __launch_bounds__(256) void k3a(const float* __restrict__ wxyz, float* __restrict__ ws){
  int bn = blockIdx.x; int b = bn >> 9; int t = threadIdx.x;
  float ri = ws[WS_RMAX + bn];
  float sx = wxyz[bn*3+0], sy = wxyz[bn*3+1];
  const unsigned* cm = (const unsigned*)ws + WS_CMAX;
  float q[9];
  #pragma unroll
  for (int j = 0; j < 9; ++j) q[j] = 0.f;
  #pragma unroll
  for (int k = 0; k < 2; ++k){
    int m = t + k*256;
    float2 d = *(const float2*)(ws + WS_DXY + (size_t)(b*M_+m)*2);
    float ex = sx-d.x, ey = sy-d.y;
    float en = sqrtf(ex*ex + ey*ey);
    float cv = ws[WS_COS + (size_t)bn*M_ + m];
    float ci = cinv(cm[b*M_ + m]);
    float s2 = cv*ci;
    q[0]+=en; q[1]+=cv; q[2]+=s2; q[3]+=en*en; q[4]+=cv*cv; q[5]+=s2*s2;
    q[6]+=en*cv; q[7]+=en*s2; q[8]+=cv*cv*ci;
  }
  #pragma unroll
  for (int j = 0; j < 9; ++j){
    float v = q[j];
    v += __shfl_xor(v,1); v += __shfl_xor(v,2); v += __shfl_xor(v,4);
    v += __shfl_xor(v,8); v += __shfl_xor(v,16); v += __shfl_xor(v,32);
    q[j] = v;
  }
  __shared__ float wr[9][4];
  int w = t >> 6;
  if ((t & 63) == 0){
    #pragma unroll
    for (int j = 0; j < 9; ++j) wr[j][w] = q[j];
  }
  __syncthreads();
  if (t < 9){
    float Q = wr[t][0] + wr[t][1] + wr[t][2] + wr[t][3];
    float f = (t==1 || t==6 || t==8) ? ri : ((t==4) ? ri*ri : 1.0f);
    float s = f*Q;
    if (t < 3) ws[WS_ROWS + t*1024 + bn] = s;   // REN, RS1, RS2
    atomicAdd(&ws[WS_SC2P + (bn & 63)*16 + t], s);
  }
}

// ---------------- K3s: closed-form BN1 per o -> A1/C1; write P0, W9S, Vf ----------------
// CS2 scaling (formerly k2f) applied inline: cs2 = raw_colsum * cinv(CMAX).
__global__ __launch_bounds__(256) void k3s(const float* __restrict__ W1,
    const float* __restrict__ b1, const float* __restrict__ g1,
    const float* __restrict__ be1, float* __restrict__ ws){
  int o = blockIdx.x; int t = threadIdx.x;
  __shared__ float scal[9];
  __shared__ float wr[12][4];
  __shared__ float sA1, sC1;
  if (t < 9){
    float s = 0.f;
    #pragma unroll 8
    for (int r = 0; r < 64; ++r) s += ws[WS_SC2P + r*16 + t];
    scal[t] = s;
  }
  const unsigned* cm = (const unsigned*)ws + WS_CMAX;
  float b1o = b1[o];
  float uu[4], vv[4];
  float a[12];
  #pragma unroll
  for (int j = 0; j < 12; ++j) a[j] = 0.f;
  #pragma unroll
  for (int k = 0; k < 4; ++k){
    int i = t + k*256;
    float u = ws[WS_U + (size_t)i*O1 + o] + b1o;
    float v = ws[WS_V + (size_t)i*O1 + o];
    uu[k] = u; vv[k] = v;
    float ren = ws[WS_ROWS + i], rs1 = ws[WS_ROWS + 1024 + i], rs2 = ws[WS_ROWS + 2048 + i];
    float cen = ws[WS_COLS + i], cs1 = ws[WS_COLS + 1024 + i];
    float cs2 = ws[WS_COLS + 2048 + i] * cinv(cm[i]);
    a[0]+=u; a[1]+=u*u; a[2]+=u*ren; a[3]+=u*rs1; a[4]+=u*rs2;
    a[5]+=v; a[6]+=v*v; a[7]+=v*cen; a[8]+=v*cs1; a[9]+=v*cs2;
    if (k < 2){ a[10]+=u; a[11]+=v; }   // b=0 partial sums
  }
  #pragma unroll
  for (int j = 0; j < 12; ++j){
    float v = a[j];
    v += __shfl_xor(v,1); v += __shfl_xor(v,2); v += __shfl_xor(v,4);
    v += __shfl_xor(v,8); v += __shfl_xor(v,16); v += __shfl_xor(v,32);
    a[j] = v;
  }
  int w = t >> 6;
  if ((t & 63) == 0){
    #pragma unroll
    for (int j = 0; j < 12; ++j) wr[j][w] = a[j];
  }
  __syncthreads();
  if (t == 0){
    float A[12];
    #pragma unroll
    for (int j = 0; j < 12; ++j) A[j] = wr[j][0] + wr[j][1] + wr[j][2] + wr[j][3];
    float w9 = W1[9*O1+o], wa = W1[138*O1+o], wb = W1[139*O1+o];
    float S1 = 512.f*(A[0] + A[5]) + w9*scal[0] + wa*scal[1] + wb*scal[2];
    float Q1 = 512.f*(A[1] + A[6])
      + 2.f*(A[10]*A[11] + (A[0]-A[10])*(A[5]-A[11]))
      + w9*w9*scal[3] + wa*wa*scal[4] + wb*wb*scal[5]
      + 2.f*(w9*wa*scal[6] + w9*wb*scal[7] + wa*wb*scal[8])
      + 2.f*(w9*A[2] + wa*A[3] + wb*A[4])
      + 2.f*(w9*A[7] + wa*A[8] + wb*A[9]);
    float mu = S1/PBIG, var = Q1/PBIG - mu*mu;
    float istd = rsqrtf(var + 1e-5f);
    float A1v = g1[o]*istd;
    sA1 = A1v; sC1 = be1[o] - mu*A1v;
    ws[WS_W9S + o]       = w9*A1v;
    ws[WS_W9S + 128 + o] = wa*A1v;
    ws[WS_W9S + 256 + o] = wb*A1v;
  }
  __syncthreads();
  float A1 = sA1, C1 = sC1;
  int k0q = o >> 5, quad = (o >> 3) & 3, j = o & 7;
  #pragma unroll
  for (int k = 0; k < 4; ++k){
    int i = t + k*256;
    ws[WS_P0 + (size_t)i*O1 + o] = uu[k]*A1 + C1;
    int b = i >> 9, m = i & 511;
    int mc = m >> 7, w2 = (m >> 5) & 3, mt = (m >> 4) & 1, l16 = m & 15;
    ws[WS_VF + (size_t)(((b*4 + mc)*4 + w2)*4096) + k0q*1024 + mt*512 + (quad*16 + l16)*8 + j]
      = vv[k]*A1;
  }
}

// ---------------- K4: fragment-packed V loads; uint4 x2 store; CMAX decoded inline ------
// block=256, min 4 waves/EU: NO scratch spill ((256,8) forced VGPR=32 and spilled).
__global__ __launch_bounds__(256, 4) void k4(const float* __restrict__ wxyz,
    float* __restrict__ ws){
  int blk = blockIdx.x; int bn = blk >> 2, mc = blk & 3;
  int b = bn >> 9; int t = threadIdx.x;
  __shared__ __align__(16) unsigned short wBf[8192];        // 16 KB fragment-packed W2
  __shared__ __align__(16) float p0s[128], w9s[128], was[128], wbs[128];
  __shared__ float ls[64], lq[64];
  {   // stage W2 fragments: lane-consecutive 16B (conflict-free)
    const s8v* g = (const s8v*)(ws + WS_W2F);
    s8v* l = (s8v*)wBf;
    #pragma unroll
    for (int c2 = 0; c2 < 4; ++c2) l[c2*256 + t] = g[c2*256 + t];
  }
  if (t < 64){ ls[t] = 0.f; lq[t] = 0.f; }
  if (t < 128){
    p0s[t] = ws[WS_P0 + bn*O1 + t];
    w9s[t] = ws[WS_W9S + t];
    was[t] = ws[WS_W9S + 128 + t];
    wbs[t] = ws[WS_W9S + 256 + t];
  }
  __syncthreads();
  int ll = t & 63, w = t >> 6, l16 = ll & 15, quad = ll >> 4;
  float sx = wxyz[bn*3+0], sy = wxyz[bn*3+1];
  float ri = ws[WS_RMAX + bn];
  const unsigned* cm = (const unsigned*)ws + WS_CMAX;
  uint4* xf4 = (uint4*)(ws + WS_X2) + (size_t)bn*4096;
  union U8 { s8v v; unsigned u[4]; };
  int mA = mc*128 + w*32 + l16, mB = mA + 16;
  float2 dA = *(const float2*)(ws + WS_DXY + (size_t)(b*M_+mA)*2);
  float2 dB = *(const float2*)(ws + WS_DXY + (size_t)(b*M_+mB)*2);
  float cvA = ws[WS_COS + (size_t)bn*M_ + mA], cvB = ws[WS_COS + (size_t)bn*M_ + mB];
  float ciA = cinv(cm[b*M_ + mA]),             ciB = cinv(cm[b*M_ + mB]);
  float exA = sx-dA.x, eyA = sy-dA.y; float en0 = sqrtf(exA*exA + eyA*eyA);
  float exB = sx-dB.x, eyB = sy-dB.y; float en1 = sqrtf(exB*exB + eyB*eyB);
  float s10 = cvA*ri, s20 = cvA*ciA;
  float s11 = cvB*ri, s21 = cvB*ciB;
  const float* vfb = ws + WS_VF + (size_t)(((b*4 + mc)*4 + w)*4096) + ll*8;
  f4v acc[2][4];
  #pragma unroll
  for (int i = 0; i < 2; ++i)
    #pragma unroll
    for (int j = 0; j < 4; ++j) acc[i][j] = (f4v){0.f,0.f,0.f,0.f};
  #pragma unroll
  for (int k0q = 0; k0q < 4; ++k0q){
    int ko = k0q*32 + quad*8;
    f4v p0a = *(const f4v*)&p0s[ko], p0b = *(const f4v*)&p0s[ko+4];
    f4v w9a = *(const f4v*)&w9s[ko], w9b = *(const f4v*)&w9s[ko+4];
    f4v waa = *(const f4v*)&was[ko], wab = *(const f4v*)&was[ko+4];
    f4v wba = *(const f4v*)&wbs[ko], wbb = *(const f4v*)&wbs[ko+4];
    const float* vA = vfb + k0q*1024;
    const float* vB = vA + 512;
    f4v vA0 = *(const f4v*)(vA), vA1 = *(const f4v*)(vA + 4);
    f4v vB0 = *(const f4v*)(vB), vB1 = *(const f4v*)(vB + 4);
    f4v zaA = relu4(p0a + vA0 + en0*w9a + s10*waa + s20*wba);
    f4v zbA = relu4(p0b + vA1 + en0*w9b + s10*wab + s20*wbb);
    f4v zaB = relu4(p0a + vB0 + en1*w9a + s11*waa + s21*wba);
    f4v zbB = relu4(p0b + vB1 + en1*w9b + s11*wab + s21*wbb);
    U8 uA, uB;
    uA.u[0] = pk_trunc(zaA[0], zaA[1]); uA.u[1] = pk_trunc(zaA[2], zaA[3]);
    uA.u[2] = pk_trunc(zbA[0], zbA[1]); uA.u[3] = pk_trunc(zbA[2], zbA[3]);
    uB.u[0] = pk_trunc(zaB[0], zaB[1]); uB.u[1] = pk_trunc(zaB[2], zaB[3]);
    uB.u[2] = pk_trunc(zbB[0], zbB[1]); uB.u[3] = pk_trunc(zbB[2], zbB[3]);
    #pragma unroll
    for (int ct = 0; ct < 4; ++ct){
      s8v bw = *(const s8v*)&wBf[((k0q*4 + ct)*64 + ll)*8];
      acc[0][ct] = __builtin_amdgcn_mfma_f32_16x16x32_bf16(bw, uA.v, acc[0][ct], 0,0,0);
      acc[1][ct] = __builtin_amdgcn_mfma_f32_16x16x32_bf16(bw, uB.v, acc[1][ct], 0,0,0);
    }
  }
  // fragment-major store, 16 B/lane: wave writes 1024 B contiguous per inst
  #pragma unroll
  for (int mt = 0; mt < 2; ++mt){
    uint4 u0, u1;
    u0.x = pk2(acc[mt][0][0], acc[mt][0][1]); u0.y = pk2(acc[mt][0][2], acc[mt][0][3]);
    u0.z = pk2(acc[mt][1][0], acc[mt][1][1]); u0.w = pk2(acc[mt][1][2], acc[mt][1][3]);
    u1.x = pk2(acc[mt][2][0], acc[mt][2][1]); u1.y = pk2(acc[mt][2][2], acc[mt][2][3]);
    u1.z = pk2(acc[mt][3][0], acc[mt][3][1]); u1.w = pk2(acc[mt][3][2], acc[mt][3][3]);
    xf4[((((mc*4 + w)*2 + mt)*2 + 0)*64) + ll] = u0;
    xf4[((((mc*4 + w)*2 + mt)*2 + 1)*64) + ll] = u1;
  }
  // BN2 stat reduce: over the 16 lanes of each quad-group, then LDS
  #pragma unroll
  for (int ct = 0; ct < 4; ++ct){
    #pragma unroll
    for (int r = 0; r < 4; ++r){
      float a0 = acc[0][ct][r], a1 = acc[1][ct][r];
      float s = a0 + a1;
      float q = a0*a0 + a1*a1;
      s += __shfl_xor(s,1); s += __shfl_xor(s,2); s += __shfl_xor(s,4); s += __shfl_xor(s,8);
      q += __shfl_xor(q,1); q += __shfl_xor(q,2); q += __shfl_xor(q,4); q += __shfl_xor(q,8);
      if (l16 == 0){
        atomicAdd(&ls[ct*16 + quad*4 + r], s);
        atomicAdd(&lq[ct*16 + quad*4 + r], q);
      }
    }
  }
  __syncthreads();
  int rep = blk & 63;
  if (t < 64) atomicAdd(&ws[WS_ST2 + rep*128 + t], ls[t]);
  else if (t < 128) atomicAdd(&ws[WS_ST2 + rep*128 + t], lq[t-64]);
}

// ---------------- K5: BN2 + softmax pool from uint4 fragment-major x2 ----------------
__global__ __launch_bounds__(256) void k5(const float* __restrict__ g2,
    const float* __restrict__ be2, const float* __restrict__ M1w,
    const float* __restrict__ M1b, float* __restrict__ ws){
  int bn = blockIdx.x; int t = threadIdx.x;
  __shared__ float sa2[64], sc2[64];
  __shared__ float s_mx[512];
  __shared__ float s_aw[512];
  __shared__ float red[256];
  __shared__ float part[64*65];
  __shared__ float s_att[64];
  __shared__ float sgmax, sinvS;
  if (t < 64){
    float s = 0.f, q = 0.f;
    #pragma unroll 8
    for (int r = 0; r < 64; ++r){ s += ws[WS_ST2 + r*128 + t]; q += ws[WS_ST2 + r*128 + 64 + t]; }
    float mu = s/PBIG, var = q/PBIG - mu*mu;
    float istd = rsqrtf(var + 1e-5f);
    float A2 = g2[t]*istd;
    sa2[t] = A2; sc2[t] = be2[t] - mu*A2;
  }
  __syncthreads();
  int ll = t & 63, w = t >> 6, l16 = ll & 15, quad = ll >> 4;
  const uint4* xf4 = (const uint4*)(ws + WS_X2) + (size_t)bn*4096;
  uint4 xv[4][2][2];   // [mc][mt][cp]
  #pragma unroll
  for (int mc = 0; mc < 4; ++mc)
    #pragma unroll
    for (int mt = 0; mt < 2; ++mt)
      #pragma unroll
      for (int cp = 0; cp < 2; ++cp)
        xv[mc][mt][cp] = xf4[((((mc*4 + w)*2 + mt)*2 + cp)*64) + ll];
  float a2r[4][4], c2r[4][4];
  #pragma unroll
  for (int ct = 0; ct < 4; ++ct)
    #pragma unroll
    for (int r = 0; r < 4; ++r){
      int c = ct*16 + quad*4 + r;
      a2r[ct][r] = sa2[c]; c2r[ct][r] = sc2[c];
    }
  // Pass A: per-m max over channels; 2 shuffles (across quads)
  #pragma unroll
  for (int mc = 0; mc < 4; ++mc){
    #pragma unroll
    for (int mt = 0; mt < 2; ++mt){
      float mx = 0.f;   // relu >= 0
      #pragma unroll
      for (int cp = 0; cp < 2; ++cp){
        uint4 uv = xv[mc][mt][cp];
        int c0t = 2*cp, c1t = 2*cp + 1;
        float x0 = bf2f((unsigned short)(uv.x & 0xffffu));
        float x1 = bf2f((unsigned short)(uv.x >> 16));
        float x2 = bf2f((unsigned short)(uv.y & 0xffffu));
        float x3 = bf2f((unsigned short)(uv.y >> 16));
        float x4 = bf2f((unsigned short)(uv.z & 0xffffu));
        float x5 = bf2f((unsigned short)(uv.z >> 16));
        float x6 = bf2f((unsigned short)(uv.w & 0xffffu));
        float x7 = bf2f((unsigned short)(uv.w >> 16));
        mx = fmaxf(mx, a2r[c0t][0]*x0 + c2r[c0t][0]);
        mx = fmaxf(mx, a2r[c0t][1]*x1 + c2r[c0t][1]);
        mx = fmaxf(mx, a2r[c0t][2]*x2 + c2r[c0t][2]);
        mx = fmaxf(mx, a2r[c0t][3]*x3 + c2r[c0t][3]);
        mx = fmaxf(mx, a2r[c1t][0]*x4 + c2r[c1t][0]);
        mx = fmaxf(mx, a2r[c1t][1]*x5 + c2r[c1t][1]);
        mx = fmaxf(mx, a2r[c1t][2]*x6 + c2r[c1t][2]);
        mx = fmaxf(mx, a2r[c1t][3]*x7 + c2r[c1t][3]);
      }
      mx = fmaxf(mx, __shfl_xor(mx,16));
      mx = fmaxf(mx, __shfl_xor(mx,32));
      if (quad == 0) s_mx[mc*128 + w*32 + mt*16 + l16] = mx;
    }
  }
  __syncthreads();
  red[t] = fmaxf(s_mx[t], s_mx[t+256]);
  __syncthreads();
  for (int s = 128; s > 0; s >>= 1){ if (t < s) red[t] = fmaxf(red[t], red[t+s]); __syncthreads(); }
  if (t == 0) sgmax = red[0];
  __syncthreads();
  float e0 = expf(s_mx[t] - sgmax), e1 = expf(s_mx[t+256] - sgmax);
  s_aw[t] = e0; s_aw[t+256] = e1;
  red[t] = e0 + e1;
  __syncthreads();
  for (int s = 128; s > 0; s >>= 1){ if (t < s) red[t] += red[t+s]; __syncthreads(); }
  if (t == 0) sinvS = 1.0f / red[0];
  __syncthreads();
  // Pass C: weighted sum (y recomputed from registers)
  float acc[4][4];
  #pragma unroll
  for (int ct = 0; ct < 4; ++ct)
    #pragma unroll
    for (int r = 0; r < 4; ++r) acc[ct][r] = 0.f;
  #pragma unroll
  for (int mc = 0; mc < 4; ++mc){
    #pragma unroll
    for (int mt = 0; mt < 2; ++mt){
      float aw = s_aw[mc*128 + w*32 + mt*16 + l16];
      #pragma unroll
      for (int cp = 0; cp < 2; ++cp){
        uint4 uv = xv[mc][mt][cp];
        int c0t = 2*cp, c1t = 2*cp + 1;
        float x0 = bf2f((unsigned short)(uv.x & 0xffffu));
        float x1 = bf2f((unsigned short)(uv.x >> 16));
        float x2 = bf2f((unsigned short)(uv.y & 0xffffu));
        float x3 = bf2f((unsigned short)(uv.y >> 16));
        float x4 = bf2f((unsigned short)(uv.z & 0xffffu));
        float x5 = bf2f((unsigned short)(uv.z >> 16));
        float x6 = bf2f((unsigned short)(uv.w & 0xffffu));
        float x7 = bf2f((unsigned short)(uv.w >> 16));
        acc[c0t][0] += aw*fmaxf(a2r[c0t][0]*x0 + c2r[c0t][0], 0.f);
        acc[c0t][1] += aw*fmaxf(a2r[c0t][1]*x1 + c2r[c0t][1], 0.f);
        acc[c0t][2] += aw*fmaxf(a2r[c0t][2]*x2 + c2r[c0t][2], 0.f);
        acc[c0t][3] += aw*fmaxf(a2r[c0t][3]*x3 + c2r[c0t][3], 0.f);
        acc[c1t][0] += aw*fmaxf(a2r[c1t][0]*x4 + c2r[c1t][0], 0.f);
        acc[c1t][1] += aw*fmaxf(a2r[c1t][1]*x5 + c2r[c1t][1], 0.f);
        acc[c1t][2] += aw*fmaxf(a2r[c1t][2]*x6 + c2r[c1t][2], 0.f);
        acc[c1t][3] += aw*fmaxf(a2r[c1t][3]*x7 + c2r[c1t][3], 0.f);
      }
    }
  }
  int row = w*16 + l16;
  #pragma unroll
  for (int ct = 0; ct < 4; ++ct)
    #pragma unroll
    for (int r = 0; r < 4; ++r)
      part[row*65 + ct*16 + quad*4 + r] = acc[ct][r];
  __syncthreads();
  if (t < 64){
    float a = 0.f;
    #pragma unroll 8
    for (int r = 0; r < 64; ++r) a += part[r*65 + t];
    s_att[t] = a * sinvS;
  }
  __syncthreads();
  if (t < 32){
    float z = M1b[t];
    #pragma unroll 8
    for (int c = 0; c < 64; ++c) z += s_att[c]*M1w[c*32 + t];
    ws[WS_Z + bn*32 + t] = z;
    int rep = bn & 63;
    atomicAdd(&ws[WS_ST3 + rep*64 + t], z);
    atomicAdd(&ws[WS_ST3 + rep*64 + 32 + t], z*z);
  }
}

// ---------------- K6: BN3 + head L2 -> logits ----------------
__global__ __launch_bounds__(256) void k6(const float* __restrict__ M1g,
    const float* __restrict__ M1be, const float* __restrict__ M2w,
    const float* __restrict__ M2b, const float* __restrict__ ws, float* __restrict__ out){
  int t = threadIdx.x; int s = blockIdx.x*256 + t;
  __shared__ float sa3[32], sc3[32];
  if (t < 32){
    float su = 0.f, q = 0.f;
    #pragma unroll 8
    for (int r = 0; r < 64; ++r){ su += ws[WS_ST3 + r*64 + t]; q += ws[WS_ST3 + r*64 + 32 + t]; }
    float mu = su/P3, var = q/P3 - mu*mu;
    float istd = rsqrtf(var + 1e-5f);
    float A3 = M1g[t]*istd;
    sa3[t] = A3; sc3[t] = M1be[t] - mu*A3;
  }
  __syncthreads();
  float a0 = M2b[0], a1 = M2b[1];
  #pragma unroll
  for (int j = 0; j < 32; ++j){
    float y = fmaxf(ws[WS_Z + s*32 + j]*sa3[j] + sc3[j], 0.f);
    a0 += y*M2w[j*2+0]; a1 += y*M2w[j*2+1];
  }
  out[s*2+0] = a0; out[s*2+1] = a1;
}

extern "C" void kernel_launch(void* const* d_in, const int* in_sizes, int n_in,
                              void* d_out, int out_size, void* d_ws, size_t ws_size,
                              hipStream_t stream){
  const float* wxyz = (const float*)d_in[0];
  const float* wpts = (const float*)d_in[1];
  const float* rf3  = (const float*)d_in[2];
  const float* rf3i = (const float*)d_in[3];
  const float* lz   = (const float*)d_in[4];
  const float* W1   = (const float*)d_in[5];
  const float* b1   = (const float*)d_in[6];
  const float* g1   = (const float*)d_in[7];
  const float* be1  = (const float*)d_in[8];
  const float* W2   = (const float*)d_in[9];
  const float* g2   = (const float*)d_in[11];
  const float* be2  = (const float*)d_in[12];
  const float* M1w  = (const float*)d_in[13];
  const float* M1b  = (const float*)d_in[14];
  const float* M1g  = (const float*)d_in[15];
  const float* M1be = (const float*)d_in[16];
  const float* M2w  = (const float*)d_in[17];
  const float* M2b  = (const float*)d_in[18];
  float* ws  = (float*)d_ws;
  float* out = (float*)d_out;
  // zero SC2P+ST2+ST3 (contiguous 935936..949248 = 13312 floats); COLS+CMAX zeroed by k2 spares
  hipMemsetAsync(ws + WS_SC2P, 0, 13312*sizeof(float), stream);
  k1 <<<2049,128,0,stream>>>(wxyz, wpts, lz, rf3, rf3i, W1, W2, ws);
  k2 <<<1028,256,0,stream>>>(ws);
  k2r<<<512,256,0,stream>>>(wxyz, ws);
  k3a<<<1024,256,0,stream>>>(wxyz, ws);
  k3s<<<128,256,0,stream>>>(W1, b1, g1, be1, ws);
  k4 <<<4096,256,0,stream>>>(wxyz, ws);
  k5 <<<1024,256,0,stream>>>(g2, be2, M1w, M1b, ws);
  k6 <<<4,256,0,stream>>>(M1g, M1be, M2w, M2b, ws, out);
}